// Round 2
// baseline (453.830 us; speedup 1.0000x reference)
//
#include <hip/hip_runtime.h>
#include <math.h>

// ---------------------------------------------------------------------------
// RTF-SSM block, MI355X. FFT path replaced by:
//   K = impulse response of B(z)/A(z) via 64-tap recurrence, truncated at 512
//   (spectral radius ~0.95 -> truncation error ~1e-7).
//   causal conv = Toeplitz-block bf16 MFMA (16x16x32), A-frags prebuilt.
//   3 GEMMs (65536x256x256) bf16 MFMA with fused bias/gelu/skip/LN/max.
// R1 fix: LDS staging loops covered only half the K-slice (2 of 4 uint4
// chunks per row) in gemm1 W, gemm2/3 W and A tiles -> uninit LDS -> NaN.
// ---------------------------------------------------------------------------

#define BSZ   8
#define SEQ   8192
#define CHN   256
#define ORD   64
#define STAPS 512
#define NDD   17            // d-pairs: covers d = 0..33 (taps to 543 >= 511)
#define PREPAD 544          // history prepad (>= 528 needed), 16-aligned
#define XROW  (PREPAD + SEQ) // 8736 elems per (b,c) row of xe^T
#define MTOT  (BSZ * SEQ)   // 65536
#define YELEMS (MTOT * CHN) // 16777216

typedef short s16x8 __attribute__((ext_vector_type(8)));
typedef float f32x4 __attribute__((ext_vector_type(4)));

#define MFMA16(a, b, c) __builtin_amdgcn_mfma_f32_16x16x32_bf16((a), (b), (c), 0, 0, 0)

__device__ __forceinline__ unsigned short f2bf(float f) {
  unsigned u = __float_as_uint(f);
  return (unsigned short)((u + 0x7FFFu + ((u >> 16) & 1u)) >> 16);
}
__device__ __forceinline__ float bf2f(unsigned short h) {
  return __uint_as_float(((unsigned)h) << 16);
}
__device__ __forceinline__ float geluf(float x) {
  return 0.5f * x * (1.0f + erff(x * 0.70710678118654752f));
}
__device__ __forceinline__ uint4 packbf8(float4 a, float4 b) {
  uint4 r;
  r.x = (unsigned)f2bf(a.x) | ((unsigned)f2bf(a.y) << 16);
  r.y = (unsigned)f2bf(a.z) | ((unsigned)f2bf(a.w) << 16);
  r.z = (unsigned)f2bf(b.x) | ((unsigned)f2bf(b.y) << 16);
  r.w = (unsigned)f2bf(b.z) | ((unsigned)f2bf(b.w) << 16);
  return r;
}

// ---------------------------------------------------------------- weights->bf16
__global__ __launch_bounds__(256) void k_prep(const float* we, const float* wf,
                                              const float* wd, unsigned short* owe,
                                              unsigned short* owf, unsigned short* owd) {
  int i = blockIdx.x * 256 + threadIdx.x;       // grid 768 -> 196608
  int which = i >> 16, off = i & 65535;
  if (which == 0)      owe[off] = f2bf(we[off]);
  else if (which == 1) owf[off] = f2bf(wf[off]);
  else                 owd[off] = f2bf(wd[off]);
}

// ------------------------------------------------- zero prepads + max buffers
__global__ __launch_bounds__(256) void k_zero(unsigned short* xeT, uint4* maxbufs) {
  int i = blockIdx.x * 256 + threadIdx.x;       // grid 548
  uint4 z; z.x = 0; z.y = 0; z.z = 0; z.w = 0;
  if (i < 2048 * 68) {                          // 544 elems/row = 68 x 16B chunks
    int row = i / 68, cc = i % 68;
    *(uint4*)((char*)xeT + (size_t)row * (XROW * 2) + (size_t)cc * 16) = z;
  } else {
    int j = i - 2048 * 68;
    if (j < 1024) maxbufs[j] = z;               // maxxe (8KB) + maxy (8KB)
  }
}

// ------------------------- K recurrence (one wave/channel) + Toeplitz A-frags
__global__ __launch_bounds__(256) void k_kgen(const float* A, const float* Bp,
                                              unsigned short* afr) {
  __shared__ float Kbuf[4][STAPS];
  int lane = threadIdx.x & 63, wv = threadIdx.x >> 6;
  int c = blockIdx.x * 4 + wv;                  // grid 64
  float a  = A[(size_t)c * ORD + lane];         // coeff for K[t-1-lane]
  float bv = Bp[(size_t)c * ORD + lane];
  float hist = 0.f;
  for (int t = 0; t < STAPS; ++t) {
    float p = a * hist;
    p += __shfl_xor(p, 1);  p += __shfl_xor(p, 2);  p += __shfl_xor(p, 4);
    p += __shfl_xor(p, 8);  p += __shfl_xor(p, 16); p += __shfl_xor(p, 32);
    float bt = (t < ORD) ? __shfl(bv, t) : 0.f;
    float nk = bt - p;
    if (lane == 0) Kbuf[wv][t] = nk;
    hist = __shfl_up(hist, 1);
    if (lane == 0) hist = nk;
  }
  __syncthreads();
  // A-frag: lane holds A[m=lane&15][k=quad*8+j]; k<16 -> T_{2dd}, k>=16 -> T_{2dd+1}
  int m = lane & 15, quad = lane >> 4;
  for (int dd = 0; dd < NDD; ++dd) {
    unsigned short v[8];
#pragma unroll
    for (int j = 0; j < 8; ++j) {
      int k = quad * 8 + j;
      int d = 2 * dd + (k >> 4);
      int p = k & 15;
      int s = 16 * d + m - p;
      float kv = (s >= 0 && s < STAPS) ? Kbuf[wv][s] : 0.f;
      v[j] = f2bf(kv);
    }
    uint4 pk;
    pk.x = (unsigned)v[0] | ((unsigned)v[1] << 16);
    pk.y = (unsigned)v[2] | ((unsigned)v[3] << 16);
    pk.z = (unsigned)v[4] | ((unsigned)v[5] << 16);
    pk.w = (unsigned)v[6] | ((unsigned)v[7] << 16);
    *(uint4*)(afr + ((size_t)(c * NDD + dd) * 64 + lane) * 8) = pk;
  }
}

// --------------- GEMM1 (transposed out): xe^T[cout][t] = W_enc x^T + b_enc
// block: 256 cout x 64 t; wave w: rows 64w..64w+63 (4 m-tiles) x 4 n-tiles
__global__ __launch_bounds__(256) void k_gemm1(const float* x, const unsigned short* wb,
                                               const float* benc, unsigned short* xeT,
                                               unsigned int* maxxe) {
  __shared__ __align__(16) unsigned short As[256 * 40]; // W tile, pad 40 elems/row
  __shared__ __align__(16) unsigned short Bs[64 * 40];  // x tile
  int tid = threadIdx.x, lane = tid & 63, wv = tid >> 6;
  int ln15 = lane & 15, hf = lane >> 4;
  size_t t0 = (size_t)blockIdx.x * 64;          // grid 1024
  int b = (int)(t0 >> 13), tin = (int)(t0 & 8191);
  f32x4 acc[4][4];
#pragma unroll
  for (int i = 0; i < 4; ++i)
#pragma unroll
    for (int j = 0; j < 4; ++j) { acc[i][j][0]=0.f; acc[i][j][1]=0.f; acc[i][j][2]=0.f; acc[i][j][3]=0.f; }

  for (int k0 = 0; k0 < CHN; k0 += 32) {
    __syncthreads();
#pragma unroll
    for (int i = 0; i < 4; ++i) {               // stage W: 256 rows x 4 chunks
      int cch = tid + 256 * i, row = cch >> 2, h = cch & 3;
      *(uint4*)&As[row * 40 + h * 8] = *(const uint4*)(wb + (size_t)row * CHN + k0 + h * 8);
    }
    {                                           // stage x: 64x32 fp32->bf16
      int row = tid >> 2, seg = tid & 3;
      const float* src = x + (t0 + row) * CHN + k0 + seg * 8;
      float4 f0 = *(const float4*)src;
      float4 f1 = *(const float4*)(src + 4);
      *(uint4*)&Bs[row * 40 + seg * 8] = packbf8(f0, f1);
    }
    __syncthreads();
    s16x8 af[4], bfr[4];
#pragma unroll
    for (int mt = 0; mt < 4; ++mt)
      af[mt] = *(const s16x8*)&As[(64 * wv + 16 * mt + ln15) * 40 + hf * 8];
#pragma unroll
    for (int nt = 0; nt < 4; ++nt)
      bfr[nt] = *(const s16x8*)&Bs[(16 * nt + ln15) * 40 + hf * 8];
#pragma unroll
    for (int mt = 0; mt < 4; ++mt)
#pragma unroll
      for (int nt = 0; nt < 4; ++nt)
        acc[mt][nt] = MFMA16(af[mt], bfr[nt], acc[mt][nt]);
  }
  // epilogue: D[m=cout][n=t]; col=lane&15=t, row=quad*4+r
  int quad = hf;
#pragma unroll
  for (int mt = 0; mt < 4; ++mt) {
#pragma unroll
    for (int r = 0; r < 4; ++r) {
      int row = 64 * wv + 16 * mt + 4 * quad + r;
      float bias = benc[row];
      float mv = 0.f;
#pragma unroll
      for (int nt = 0; nt < 4; ++nt) {
        float v = acc[mt][nt][r] + bias;
        int t = tin + 16 * nt + ln15;
        xeT[(size_t)(b * CHN + row) * XROW + PREPAD + t] = f2bf(v);
        mv = fmaxf(mv, fabsf(v));
      }
      mv = fmaxf(mv, __shfl_xor(mv, 1)); mv = fmaxf(mv, __shfl_xor(mv, 2));
      mv = fmaxf(mv, __shfl_xor(mv, 4)); mv = fmaxf(mv, __shfl_xor(mv, 8));
      if (ln15 == 0) atomicMax(&maxxe[b * CHN + row], __float_as_uint(mv));
    }
  }
}

// ------------- conv: y1[t][c] = gelu(FIR(xe) + h0*xe); block = 8 ch x 256 t
__global__ __launch_bounds__(256) void k_conv(const unsigned short* xeT,
                                              const unsigned short* afr,
                                              unsigned short* y1, const float* h0p) {
  __shared__ __align__(16) unsigned short xet[8 * 1024]; // 8 rows x 128 chunks (swizzled)
  __shared__ __align__(16) unsigned short bnc[8 * 256];  // transpose bounce
  int tid = threadIdx.x;
  int idx = blockIdx.x;                          // grid 8192 = 8b x 32cg x 32tg
  int tg = idx & 31, cg = (idx >> 5) & 31, b = idx >> 10;
  int c0 = cg * 8, t0 = tg * 256;
  // stage xe^T tile: per channel elems [t0, t0+800) of the padded row
  for (int i = tid; i < 800; i += 256) {
    int row = i / 100, cc = i % 100;
    uint4 v = *(const uint4*)(xeT + (size_t)(b * CHN + c0 + row) * XROW + t0 + cc * 8);
    int sw = cc ^ ((cc >> 3) & 7);
    *(uint4*)&xet[row * 1024 + sw * 8] = v;
  }
  __syncthreads();
  int lane = tid & 63, wv = tid >> 6;
  int n = lane & 15, quad = lane >> 4;
  int qc = quad - ((quad >> 1) << 2);            // 0,1,-2,-1
  float h0 = h0p[0];
#pragma unroll
  for (int ci = 0; ci < 2; ++ci) {
    int cl = wv * 2 + ci;
    int c = c0 + cl;
    f32x4 acc; acc[0]=0.f; acc[1]=0.f; acc[2]=0.f; acc[3]=0.f;
    const unsigned short* ap = afr + (size_t)c * (NDD * 512) + (size_t)lane * 8;
#pragma unroll 4
    for (int dd = 0; dd < NDD; ++dd) {
      s16x8 a = *(const s16x8*)(ap + (size_t)dd * 512);
      int cc = 2 * n - 4 * dd + 68 + qc;
      int sw = cc ^ ((cc >> 3) & 7);
      s16x8 bfr = *(const s16x8*)&xet[cl * 1024 + sw * 8];
      acc = MFMA16(a, bfr, acc);
    }
#pragma unroll
    for (int r = 0; r < 4; ++r) {
      int tl = 16 * n + 4 * quad + r;
      int e = PREPAD + tl;
      int ch = e >> 3, sw = ch ^ ((ch >> 3) & 7);
      float xv = bf2f(xet[cl * 1024 + sw * 8 + (e & 7)]);
      float v = acc[r] + h0 * xv;
      bnc[cl * 256 + tl] = f2bf(geluf(v));
    }
  }
  __syncthreads();
  {                                              // coalesced 16B stores: 8 ch per t
    int tl = tid;
    uint4 pk;
    pk.x = (unsigned)bnc[0 * 256 + tl] | ((unsigned)bnc[1 * 256 + tl] << 16);
    pk.y = (unsigned)bnc[2 * 256 + tl] | ((unsigned)bnc[3 * 256 + tl] << 16);
    pk.z = (unsigned)bnc[4 * 256 + tl] | ((unsigned)bnc[5 * 256 + tl] << 16);
    pk.w = (unsigned)bnc[6 * 256 + tl] | ((unsigned)bnc[7 * 256 + tl] << 16);
    *(uint4*)(y1 + (size_t)(b * SEQ + t0 + tl) * CHN + c0) = pk;
  }
}

// ------ GEMM2: y2n = LN(gelu(y1 W_fc^T + b_fc) + xe)*gamma+beta, in-place y1
// block: 64 t x 256 cout; wave: 32 rows x 128 cols (2 m-tiles x 8 n-tiles)
__global__ __launch_bounds__(256) void k_gemm2(const unsigned short* y1,
                                               const unsigned short* wb, const float* bfc,
                                               const unsigned short* xeT, const float* gam,
                                               const float* bet, unsigned short* y2n) {
  __shared__ __align__(16) unsigned short Ws[256 * 40];
  __shared__ __align__(16) unsigned short Asb[64 * 40];
  __shared__ float pl[64][2][2];
  int tid = threadIdx.x, lane = tid & 63, wv = tid >> 6;
  int ln15 = lane & 15, hf = lane >> 4, quad = hf;
  size_t M0 = (size_t)blockIdx.x * 64;           // grid 1024
  int b = (int)(M0 >> 13), tin = (int)(M0 & 8191);
  int mh = wv & 1, nh = wv >> 1;
  f32x4 acc[2][8];
#pragma unroll
  for (int i = 0; i < 2; ++i)
#pragma unroll
    for (int j = 0; j < 8; ++j) { acc[i][j][0]=0.f; acc[i][j][1]=0.f; acc[i][j][2]=0.f; acc[i][j][3]=0.f; }

  for (int k0 = 0; k0 < CHN; k0 += 32) {
    __syncthreads();
#pragma unroll
    for (int i = 0; i < 4; ++i) {               // stage W: 256 rows x 4 chunks
      int cch = tid + 256 * i, row = cch >> 2, h = cch & 3;
      *(uint4*)&Ws[row * 40 + h * 8] = *(const uint4*)(wb + (size_t)row * CHN + k0 + h * 8);
    }
    {                                           // stage A: 64 rows x 4 chunks
      int row = tid >> 2, h = tid & 3;
      *(uint4*)&Asb[row * 40 + h * 8] = *(const uint4*)(y1 + (M0 + row) * CHN + k0 + h * 8);
    }
    __syncthreads();
    s16x8 af[2], bfr[8];
#pragma unroll
    for (int mt = 0; mt < 2; ++mt)
      af[mt] = *(const s16x8*)&Asb[(32 * mh + 16 * mt + ln15) * 40 + hf * 8];
#pragma unroll
    for (int nt = 0; nt < 8; ++nt)
      bfr[nt] = *(const s16x8*)&Ws[(128 * nh + 16 * nt + ln15) * 40 + hf * 8];
#pragma unroll
    for (int mt = 0; mt < 2; ++mt)
#pragma unroll
      for (int nt = 0; nt < 8; ++nt)
        acc[mt][nt] = MFMA16(af[mt], bfr[nt], acc[mt][nt]);
  }
  float g8[8], be8[8], bf8[8];
#pragma unroll
  for (int nt = 0; nt < 8; ++nt) {
    int col = 128 * nh + 16 * nt + ln15;
    g8[nt] = gam[col]; be8[nt] = bet[col]; bf8[nt] = bfc[col];
  }
#pragma unroll
  for (int mt = 0; mt < 2; ++mt) {
#pragma unroll
    for (int r = 0; r < 4; ++r) {
      int ml = 32 * mh + 16 * mt + 4 * quad + r;
      float s1 = 0.f, s2 = 0.f;
#pragma unroll
      for (int nt = 0; nt < 8; ++nt) {
        int col = 128 * nh + 16 * nt + ln15;
        float t2 = acc[mt][nt][r] + bf8[nt];
        float xv = bf2f(xeT[(size_t)(b * CHN + col) * XROW + PREPAD + tin + ml]);
        float y2 = geluf(t2) + xv;
        acc[mt][nt][r] = y2;
        s1 += y2; s2 += y2 * y2;
      }
      s1 += __shfl_xor(s1, 1); s2 += __shfl_xor(s2, 1);
      s1 += __shfl_xor(s1, 2); s2 += __shfl_xor(s2, 2);
      s1 += __shfl_xor(s1, 4); s2 += __shfl_xor(s2, 4);
      s1 += __shfl_xor(s1, 8); s2 += __shfl_xor(s2, 8);
      if (ln15 == 0) { pl[ml][nh][0] = s1; pl[ml][nh][1] = s2; }
    }
  }
  __syncthreads();
#pragma unroll
  for (int mt = 0; mt < 2; ++mt) {
#pragma unroll
    for (int r = 0; r < 4; ++r) {
      int ml = 32 * mh + 16 * mt + 4 * quad + r;
      float s1 = pl[ml][0][0] + pl[ml][1][0];
      float s2 = pl[ml][0][1] + pl[ml][1][1];
      float mu = s1 * (1.f / 256.f);
      float var = s2 * (1.f / 256.f) - mu * mu;
      float ri = rsqrtf(var + 1e-5f);
#pragma unroll
      for (int nt = 0; nt < 8; ++nt) {
        int col = 128 * nh + 16 * nt + ln15;
        float yn = (acc[mt][nt][r] - mu) * ri * g8[nt] + be8[nt];
        y2n[(M0 + ml) * CHN + col] = f2bf(yn);
      }
    }
  }
}

// ------------------- GEMM3: y = y2n W_dec^T + b_dec (fp32 out) + maxy atomics
__global__ __launch_bounds__(256) void k_gemm3(const unsigned short* y2n,
                                               const unsigned short* wb, const float* bd,
                                               float* yout, unsigned int* maxy) {
  __shared__ __align__(16) unsigned short Ws[256 * 40];
  __shared__ __align__(16) unsigned short Asb[64 * 40];
  int tid = threadIdx.x, lane = tid & 63, wv = tid >> 6;
  int ln15 = lane & 15, hf = lane >> 4, quad = hf;
  size_t M0 = (size_t)blockIdx.x * 64;           // grid 1024
  int b = (int)(M0 >> 13);
  int mh = wv & 1, nh = wv >> 1;
  f32x4 acc[2][8];
#pragma unroll
  for (int i = 0; i < 2; ++i)
#pragma unroll
    for (int j = 0; j < 8; ++j) { acc[i][j][0]=0.f; acc[i][j][1]=0.f; acc[i][j][2]=0.f; acc[i][j][3]=0.f; }

  for (int k0 = 0; k0 < CHN; k0 += 32) {
    __syncthreads();
#pragma unroll
    for (int i = 0; i < 4; ++i) {               // stage W: 256 rows x 4 chunks
      int cch = tid + 256 * i, row = cch >> 2, h = cch & 3;
      *(uint4*)&Ws[row * 40 + h * 8] = *(const uint4*)(wb + (size_t)row * CHN + k0 + h * 8);
    }
    {                                           // stage A: 64 rows x 4 chunks
      int row = tid >> 2, h = tid & 3;
      *(uint4*)&Asb[row * 40 + h * 8] = *(const uint4*)(y2n + (M0 + row) * CHN + k0 + h * 8);
    }
    __syncthreads();
    s16x8 af[2], bfr[8];
#pragma unroll
    for (int mt = 0; mt < 2; ++mt)
      af[mt] = *(const s16x8*)&Asb[(32 * mh + 16 * mt + ln15) * 40 + hf * 8];
#pragma unroll
    for (int nt = 0; nt < 8; ++nt)
      bfr[nt] = *(const s16x8*)&Ws[(128 * nh + 16 * nt + ln15) * 40 + hf * 8];
#pragma unroll
    for (int mt = 0; mt < 2; ++mt)
#pragma unroll
      for (int nt = 0; nt < 8; ++nt)
        acc[mt][nt] = MFMA16(af[mt], bfr[nt], acc[mt][nt]);
  }
  float bd8[8];
#pragma unroll
  for (int nt = 0; nt < 8; ++nt) bd8[nt] = bd[128 * nh + 16 * nt + ln15];
#pragma unroll
  for (int mt = 0; mt < 2; ++mt)
#pragma unroll
    for (int r = 0; r < 4; ++r) {
      int ml = 32 * mh + 16 * mt + 4 * quad + r;
#pragma unroll
      for (int nt = 0; nt < 8; ++nt) {
        int col = 128 * nh + 16 * nt + ln15;
        float v = acc[mt][nt][r] + bd8[nt];
        acc[mt][nt][r] = v;
        yout[(M0 + ml) * CHN + col] = v;
      }
    }
#pragma unroll
  for (int nt = 0; nt < 8; ++nt) {
    int col = 128 * nh + 16 * nt + ln15;
    float mv = 0.f;
#pragma unroll
    for (int mt = 0; mt < 2; ++mt)
#pragma unroll
      for (int r = 0; r < 4; ++r) mv = fmaxf(mv, fabsf(acc[mt][nt][r]));
    mv = fmaxf(mv, __shfl_xor(mv, 16));
    mv = fmaxf(mv, __shfl_xor(mv, 32));
    if (quad == 0) atomicMax(&maxy[b * CHN + col], __float_as_uint(mv));
  }
}

// ------------------------------------------------------------ h = my/(mx+eps)
__global__ __launch_bounds__(256) void k_hfin(const unsigned int* maxxe,
                                              const unsigned int* maxy, float* hout) {
  int i = blockIdx.x * 256 + threadIdx.x;        // grid 8
  if (i < BSZ * CHN) {
    float mx = __uint_as_float(maxxe[i]);
    float my = __uint_as_float(maxy[i]);
    hout[i] = my / (mx + 1e-6f);
  }
}

// ---------------------------------------------------------------------------
extern "C" void kernel_launch(void* const* d_in, const int* in_sizes, int n_in,
                              void* d_out, int out_size, void* d_ws, size_t ws_size,
                              hipStream_t stream) {
  const float* x   = (const float*)d_in[0];
  const float* A   = (const float*)d_in[1];
  const float* Bp  = (const float*)d_in[2];
  const float* h0  = (const float*)d_in[3];
  const float* We  = (const float*)d_in[4];
  const float* be  = (const float*)d_in[5];
  const float* Wf  = (const float*)d_in[6];
  const float* bfc = (const float*)d_in[7];
  const float* gam = (const float*)d_in[8];
  const float* bet = (const float*)d_in[9];
  const float* Wd  = (const float*)d_in[10];
  const float* bd  = (const float*)d_in[11];

  char* ws = (char*)d_ws;
  unsigned short* y1  = (unsigned short*)(ws + 0);          // 33554432 B
  unsigned short* afr = (unsigned short*)(ws + 33554432);   //  4456448 B
  unsigned short* web = (unsigned short*)(ws + 38010880);   //   131072 B
  unsigned short* wfb = (unsigned short*)(ws + 38141952);
  unsigned short* wdb = (unsigned short*)(ws + 38273024);
  unsigned int*  maxxe = (unsigned int*)(ws + 38404096);    //     8192 B
  unsigned int*  maxy  = (unsigned int*)(ws + 38412288);    //     8192 B

  unsigned short* xeT = (unsigned short*)d_out;             // scratch: 35.8 MB
  float* yout = (float*)d_out;
  float* hout = yout + YELEMS;

  k_prep<<<768, 256, 0, stream>>>(We, Wf, Wd, web, wfb, wdb);
  k_zero<<<548, 256, 0, stream>>>(xeT, (uint4*)maxxe);
  k_kgen<<<64, 256, 0, stream>>>(A, Bp, afr);
  k_gemm1<<<1024, 256, 0, stream>>>(x, web, be, xeT, maxxe);
  k_conv<<<8192, 256, 0, stream>>>(xeT, afr, y1, h0);
  k_gemm2<<<1024, 256, 0, stream>>>(y1, wfb, bfc, xeT, gam, bet, y1);
  k_gemm3<<<1024, 256, 0, stream>>>(y1, wdb, bd, yout, maxy);
  k_hfin<<<8, 256, 0, stream>>>(maxxe, maxy, hout);
}

// Round 3
// 361.691 us; speedup vs baseline: 1.2547x; 1.2547x over previous
//
#include <hip/hip_runtime.h>
#include <math.h>

// ---------------------------------------------------------------------------
// RTF-SSM block, MI355X. FFT path replaced by:
//   K = impulse response of B(z)/A(z), truncated at 512 taps
//   (spectral radius ~0.95 -> truncation error ~1e-7).
//   R2: K-gen via Newton power-series inversion (9 wave-parallel doubling
//   steps) instead of the 512-step serial recurrence (was 122 us, 573
//   cyc/iter of shuffle latency chain).
//   causal conv = Toeplitz-block bf16 MFMA (16x16x32), A-frags prebuilt.
//   3 GEMMs (65536x256x256) bf16 MFMA with fused bias/gelu/skip/LN/max.
// ---------------------------------------------------------------------------

#define BSZ   8
#define SEQ   8192
#define CHN   256
#define ORD   64
#define STAPS 512
#define NDD   17            // d-pairs: covers d = 0..33 (taps to 543 >= 511)
#define PREPAD 544          // history prepad (>= 528 needed), 16-aligned
#define XROW  (PREPAD + SEQ) // 8736 elems per (b,c) row of xe^T
#define MTOT  (BSZ * SEQ)   // 65536
#define YELEMS (MTOT * CHN) // 16777216

typedef short s16x8 __attribute__((ext_vector_type(8)));
typedef float f32x4 __attribute__((ext_vector_type(4)));

#define MFMA16(a, b, c) __builtin_amdgcn_mfma_f32_16x16x32_bf16((a), (b), (c), 0, 0, 0)

__device__ __forceinline__ unsigned short f2bf(float f) {
  unsigned u = __float_as_uint(f);
  return (unsigned short)((u + 0x7FFFu + ((u >> 16) & 1u)) >> 16);
}
__device__ __forceinline__ float bf2f(unsigned short h) {
  return __uint_as_float(((unsigned)h) << 16);
}
__device__ __forceinline__ float geluf(float x) {
  return 0.5f * x * (1.0f + erff(x * 0.70710678118654752f));
}
__device__ __forceinline__ uint4 packbf8(float4 a, float4 b) {
  uint4 r;
  r.x = (unsigned)f2bf(a.x) | ((unsigned)f2bf(a.y) << 16);
  r.y = (unsigned)f2bf(a.z) | ((unsigned)f2bf(a.w) << 16);
  r.z = (unsigned)f2bf(b.x) | ((unsigned)f2bf(b.y) << 16);
  r.w = (unsigned)f2bf(b.z) | ((unsigned)f2bf(b.w) << 16);
  return r;
}

// ---------------------------------------------------------------- weights->bf16
__global__ __launch_bounds__(256) void k_prep(const float* we, const float* wf,
                                              const float* wd, unsigned short* owe,
                                              unsigned short* owf, unsigned short* owd) {
  int i = blockIdx.x * 256 + threadIdx.x;       // grid 768 -> 196608
  int which = i >> 16, off = i & 65535;
  if (which == 0)      owe[off] = f2bf(we[off]);
  else if (which == 1) owf[off] = f2bf(wf[off]);
  else                 owd[off] = f2bf(wd[off]);
}

// ------------------------------------------------- zero prepads + max buffers
__global__ __launch_bounds__(256) void k_zero(unsigned short* xeT, uint4* maxbufs) {
  int i = blockIdx.x * 256 + threadIdx.x;       // grid 548
  uint4 z; z.x = 0; z.y = 0; z.z = 0; z.w = 0;
  if (i < 2048 * 68) {                          // 544 elems/row = 68 x 16B chunks
    int row = i / 68, cc = i % 68;
    *(uint4*)((char*)xeT + (size_t)row * (XROW * 2) + (size_t)cc * 16) = z;
  } else {
    int j = i - 2048 * 68;
    if (j < 1024) maxbufs[j] = z;               // maxxe (8KB) + maxy (8KB)
  }
}

// ---------------- K-gen: Newton inversion of A(z) + B*G conv + Toeplitz frags
// one wave per channel; grid 64 x 4 waves.
// G = 1/A mod z^512 by doubling: n = 1,2,...,256. Error term E = (A*G) mod
// z^{2n} has only 64 nonzero coeffs E[n..n+63] (deg A = 64):
//   E[n+l]    = sum_{u=l+1}^{min(n+l,64)} A_u * G[n+l-u]          (l < 64)
//   G[n+idx]  = -sum_{i=0}^{min(idx,63)} E[n+i] * G[idx-i]        (idx < n)
// All reads are of already-final values -> fully parallel per step.
__global__ __launch_bounds__(256) void k_kgen(const float* A, const float* Bp,
                                              unsigned short* afr) {
  __shared__ float Gs[4][STAPS];
  __shared__ float Et[4][64];
  __shared__ float Ac[4][65];
  __shared__ float Bb[4][64];
  __shared__ float Kb[4][STAPS];
  int lane = threadIdx.x & 63, wv = threadIdx.x >> 6;
  int c = blockIdx.x * 4 + wv;                  // grid 64
  Ac[wv][lane + 1] = A[(size_t)c * ORD + lane];
  Bb[wv][lane]     = Bp[(size_t)c * ORD + lane];
  if (lane == 0) { Ac[wv][0] = 1.f; Gs[wv][0] = 1.f; }
  __syncthreads();

  for (int n = 1; n < STAPS; n <<= 1) {
    // E[n+lane]
    float e = 0.f;
    int uhi = min(n + lane, 64);
    for (int u = lane + 1; u <= uhi; ++u)
      e += Ac[wv][u] * Gs[wv][n + lane - u];
    Et[wv][lane] = e;
    __syncthreads();
    // extend G on [n, 2n)
    int nk = (n + 63) >> 6;
    for (int k = 0; k < nk; ++k) {
      int idx = k * 64 + lane;
      if (idx < n) {
        float acc = 0.f;
        int imax = min(idx, 63);
        for (int i = 0; i <= imax; ++i)
          acc += Et[wv][i] * Gs[wv][idx - i];
        Gs[wv][n + idx] = -acc;
      }
    }
    __syncthreads();
  }

  // K = B * G mod z^512
  for (int k = 0; k < 8; ++k) {
    int t = k * 64 + lane;
    float acc = 0.f;
    int jmax = min(t, 63);
    for (int j = 0; j <= jmax; ++j)
      acc += Bb[wv][j] * Gs[wv][t - j];
    Kb[wv][t] = acc;
  }
  __syncthreads();

  // A-frag: lane holds A[m=lane&15][k=quad*8+j]; k<16 -> T_{2dd}, k>=16 -> T_{2dd+1}
  int m = lane & 15, quad = lane >> 4;
  for (int dd = 0; dd < NDD; ++dd) {
    unsigned short v[8];
#pragma unroll
    for (int j = 0; j < 8; ++j) {
      int k = quad * 8 + j;
      int d = 2 * dd + (k >> 4);
      int p = k & 15;
      int s = 16 * d + m - p;
      float kv = (s >= 0 && s < STAPS) ? Kb[wv][s] : 0.f;
      v[j] = f2bf(kv);
    }
    uint4 pk;
    pk.x = (unsigned)v[0] | ((unsigned)v[1] << 16);
    pk.y = (unsigned)v[2] | ((unsigned)v[3] << 16);
    pk.z = (unsigned)v[4] | ((unsigned)v[5] << 16);
    pk.w = (unsigned)v[6] | ((unsigned)v[7] << 16);
    *(uint4*)(afr + ((size_t)(c * NDD + dd) * 64 + lane) * 8) = pk;
  }
}

// --------------- GEMM1 (transposed out): xe^T[cout][t] = W_enc x^T + b_enc
// block: 256 cout x 64 t; wave w: rows 64w..64w+63 (4 m-tiles) x 4 n-tiles
__global__ __launch_bounds__(256) void k_gemm1(const float* x, const unsigned short* wb,
                                               const float* benc, unsigned short* xeT,
                                               unsigned int* maxxe) {
  __shared__ __align__(16) unsigned short As[256 * 40]; // W tile, pad 40 elems/row
  __shared__ __align__(16) unsigned short Bs[64 * 40];  // x tile
  int tid = threadIdx.x, lane = tid & 63, wv = tid >> 6;
  int ln15 = lane & 15, hf = lane >> 4;
  size_t t0 = (size_t)blockIdx.x * 64;          // grid 1024
  int b = (int)(t0 >> 13), tin = (int)(t0 & 8191);
  f32x4 acc[4][4];
#pragma unroll
  for (int i = 0; i < 4; ++i)
#pragma unroll
    for (int j = 0; j < 4; ++j) { acc[i][j][0]=0.f; acc[i][j][1]=0.f; acc[i][j][2]=0.f; acc[i][j][3]=0.f; }

  for (int k0 = 0; k0 < CHN; k0 += 32) {
    __syncthreads();
#pragma unroll
    for (int i = 0; i < 4; ++i) {               // stage W: 256 rows x 4 chunks
      int cch = tid + 256 * i, row = cch >> 2, h = cch & 3;
      *(uint4*)&As[row * 40 + h * 8] = *(const uint4*)(wb + (size_t)row * CHN + k0 + h * 8);
    }
    {                                           // stage x: 64x32 fp32->bf16
      int row = tid >> 2, seg = tid & 3;
      const float* src = x + (t0 + row) * CHN + k0 + seg * 8;
      float4 f0 = *(const float4*)src;
      float4 f1 = *(const float4*)(src + 4);
      *(uint4*)&Bs[row * 40 + seg * 8] = packbf8(f0, f1);
    }
    __syncthreads();
    s16x8 af[4], bfr[4];
#pragma unroll
    for (int mt = 0; mt < 4; ++mt)
      af[mt] = *(const s16x8*)&As[(64 * wv + 16 * mt + ln15) * 40 + hf * 8];
#pragma unroll
    for (int nt = 0; nt < 4; ++nt)
      bfr[nt] = *(const s16x8*)&Bs[(16 * nt + ln15) * 40 + hf * 8];
#pragma unroll
    for (int mt = 0; mt < 4; ++mt)
#pragma unroll
      for (int nt = 0; nt < 4; ++nt)
        acc[mt][nt] = MFMA16(af[mt], bfr[nt], acc[mt][nt]);
  }
  // epilogue: D[m=cout][n=t]; col=lane&15=t, row=quad*4+r
  int quad = hf;
#pragma unroll
  for (int mt = 0; mt < 4; ++mt) {
#pragma unroll
    for (int r = 0; r < 4; ++r) {
      int row = 64 * wv + 16 * mt + 4 * quad + r;
      float bias = benc[row];
      float mv = 0.f;
#pragma unroll
      for (int nt = 0; nt < 4; ++nt) {
        float v = acc[mt][nt][r] + bias;
        int t = tin + 16 * nt + ln15;
        xeT[(size_t)(b * CHN + row) * XROW + PREPAD + t] = f2bf(v);
        mv = fmaxf(mv, fabsf(v));
      }
      mv = fmaxf(mv, __shfl_xor(mv, 1)); mv = fmaxf(mv, __shfl_xor(mv, 2));
      mv = fmaxf(mv, __shfl_xor(mv, 4)); mv = fmaxf(mv, __shfl_xor(mv, 8));
      if (ln15 == 0) atomicMax(&maxxe[b * CHN + row], __float_as_uint(mv));
    }
  }
}

// ------------- conv: y1[t][c] = gelu(FIR(xe) + h0*xe); block = 8 ch x 256 t
__global__ __launch_bounds__(256) void k_conv(const unsigned short* xeT,
                                              const unsigned short* afr,
                                              unsigned short* y1, const float* h0p) {
  __shared__ __align__(16) unsigned short xet[8 * 1024]; // 8 rows x 128 chunks (swizzled)
  __shared__ __align__(16) unsigned short bnc[8 * 256];  // transpose bounce
  int tid = threadIdx.x;
  int idx = blockIdx.x;                          // grid 8192 = 8b x 32cg x 32tg
  int tg = idx & 31, cg = (idx >> 5) & 31, b = idx >> 10;
  int c0 = cg * 8, t0 = tg * 256;
  // stage xe^T tile: per channel elems [t0, t0+800) of the padded row
  for (int i = tid; i < 800; i += 256) {
    int row = i / 100, cc = i % 100;
    uint4 v = *(const uint4*)(xeT + (size_t)(b * CHN + c0 + row) * XROW + t0 + cc * 8);
    int sw = cc ^ ((cc >> 3) & 7);
    *(uint4*)&xet[row * 1024 + sw * 8] = v;
  }
  __syncthreads();
  int lane = tid & 63, wv = tid >> 6;
  int n = lane & 15, quad = lane >> 4;
  int qc = quad - ((quad >> 1) << 2);            // 0,1,-2,-1
  float h0 = h0p[0];
#pragma unroll
  for (int ci = 0; ci < 2; ++ci) {
    int cl = wv * 2 + ci;
    int c = c0 + cl;
    f32x4 acc; acc[0]=0.f; acc[1]=0.f; acc[2]=0.f; acc[3]=0.f;
    const unsigned short* ap = afr + (size_t)c * (NDD * 512) + (size_t)lane * 8;
#pragma unroll 4
    for (int dd = 0; dd < NDD; ++dd) {
      s16x8 a = *(const s16x8*)(ap + (size_t)dd * 512);
      int cc = 2 * n - 4 * dd + 68 + qc;
      int sw = cc ^ ((cc >> 3) & 7);
      s16x8 bfr = *(const s16x8*)&xet[cl * 1024 + sw * 8];
      acc = MFMA16(a, bfr, acc);
    }
#pragma unroll
    for (int r = 0; r < 4; ++r) {
      int tl = 16 * n + 4 * quad + r;
      int e = PREPAD + tl;
      int ch = e >> 3, sw = ch ^ ((ch >> 3) & 7);
      float xv = bf2f(xet[cl * 1024 + sw * 8 + (e & 7)]);
      float v = acc[r] + h0 * xv;
      bnc[cl * 256 + tl] = f2bf(geluf(v));
    }
  }
  __syncthreads();
  {                                              // coalesced 16B stores: 8 ch per t
    int tl = tid;
    uint4 pk;
    pk.x = (unsigned)bnc[0 * 256 + tl] | ((unsigned)bnc[1 * 256 + tl] << 16);
    pk.y = (unsigned)bnc[2 * 256 + tl] | ((unsigned)bnc[3 * 256 + tl] << 16);
    pk.z = (unsigned)bnc[4 * 256 + tl] | ((unsigned)bnc[5 * 256 + tl] << 16);
    pk.w = (unsigned)bnc[6 * 256 + tl] | ((unsigned)bnc[7 * 256 + tl] << 16);
    *(uint4*)(y1 + (size_t)(b * SEQ + t0 + tl) * CHN + c0) = pk;
  }
}

// ------ GEMM2: y2n = LN(gelu(y1 W_fc^T + b_fc) + xe)*gamma+beta, in-place y1
// block: 64 t x 256 cout; wave: 32 rows x 128 cols (2 m-tiles x 8 n-tiles)
__global__ __launch_bounds__(256) void k_gemm2(const unsigned short* y1,
                                               const unsigned short* wb, const float* bfc,
                                               const unsigned short* xeT, const float* gam,
                                               const float* bet, unsigned short* y2n) {
  __shared__ __align__(16) unsigned short Ws[256 * 40];
  __shared__ __align__(16) unsigned short Asb[64 * 40];
  __shared__ float pl[64][2][2];
  int tid = threadIdx.x, lane = tid & 63, wv = tid >> 6;
  int ln15 = lane & 15, hf = lane >> 4, quad = hf;
  size_t M0 = (size_t)blockIdx.x * 64;           // grid 1024
  int b = (int)(M0 >> 13), tin = (int)(M0 & 8191);
  int mh = wv & 1, nh = wv >> 1;
  f32x4 acc[2][8];
#pragma unroll
  for (int i = 0; i < 2; ++i)
#pragma unroll
    for (int j = 0; j < 8; ++j) { acc[i][j][0]=0.f; acc[i][j][1]=0.f; acc[i][j][2]=0.f; acc[i][j][3]=0.f; }

  for (int k0 = 0; k0 < CHN; k0 += 32) {
    __syncthreads();
#pragma unroll
    for (int i = 0; i < 4; ++i) {               // stage W: 256 rows x 4 chunks
      int cch = tid + 256 * i, row = cch >> 2, h = cch & 3;
      *(uint4*)&Ws[row * 40 + h * 8] = *(const uint4*)(wb + (size_t)row * CHN + k0 + h * 8);
    }
    {                                           // stage A: 64 rows x 4 chunks
      int row = tid >> 2, h = tid & 3;
      *(uint4*)&Asb[row * 40 + h * 8] = *(const uint4*)(y1 + (M0 + row) * CHN + k0 + h * 8);
    }
    __syncthreads();
    s16x8 af[2], bfr[8];
#pragma unroll
    for (int mt = 0; mt < 2; ++mt)
      af[mt] = *(const s16x8*)&Asb[(32 * mh + 16 * mt + ln15) * 40 + hf * 8];
#pragma unroll
    for (int nt = 0; nt < 8; ++nt)
      bfr[nt] = *(const s16x8*)&Ws[(128 * nh + 16 * nt + ln15) * 40 + hf * 8];
#pragma unroll
    for (int mt = 0; mt < 2; ++mt)
#pragma unroll
      for (int nt = 0; nt < 8; ++nt)
        acc[mt][nt] = MFMA16(af[mt], bfr[nt], acc[mt][nt]);
  }
  float g8[8], be8[8], bf8[8];
#pragma unroll
  for (int nt = 0; nt < 8; ++nt) {
    int col = 128 * nh + 16 * nt + ln15;
    g8[nt] = gam[col]; be8[nt] = bet[col]; bf8[nt] = bfc[col];
  }
#pragma unroll
  for (int mt = 0; mt < 2; ++mt) {
#pragma unroll
    for (int r = 0; r < 4; ++r) {
      int ml = 32 * mh + 16 * mt + 4 * quad + r;
      float s1 = 0.f, s2 = 0.f;
#pragma unroll
      for (int nt = 0; nt < 8; ++nt) {
        int col = 128 * nh + 16 * nt + ln15;
        float t2 = acc[mt][nt][r] + bf8[nt];
        float xv = bf2f(xeT[(size_t)(b * CHN + col) * XROW + PREPAD + tin + ml]);
        float y2 = geluf(t2) + xv;
        acc[mt][nt][r] = y2;
        s1 += y2; s2 += y2 * y2;
      }
      s1 += __shfl_xor(s1, 1); s2 += __shfl_xor(s2, 1);
      s1 += __shfl_xor(s1, 2); s2 += __shfl_xor(s2, 2);
      s1 += __shfl_xor(s1, 4); s2 += __shfl_xor(s2, 4);
      s1 += __shfl_xor(s1, 8); s2 += __shfl_xor(s2, 8);
      if (ln15 == 0) { pl[ml][nh][0] = s1; pl[ml][nh][1] = s2; }
    }
  }
  __syncthreads();
#pragma unroll
  for (int mt = 0; mt < 2; ++mt) {
#pragma unroll
    for (int r = 0; r < 4; ++r) {
      int ml = 32 * mh + 16 * mt + 4 * quad + r;
      float s1 = pl[ml][0][0] + pl[ml][1][0];
      float s2 = pl[ml][0][1] + pl[ml][1][1];
      float mu = s1 * (1.f / 256.f);
      float var = s2 * (1.f / 256.f) - mu * mu;
      float ri = rsqrtf(var + 1e-5f);
#pragma unroll
      for (int nt = 0; nt < 8; ++nt) {
        int col = 128 * nh + 16 * nt + ln15;
        float yn = (acc[mt][nt][r] - mu) * ri * g8[nt] + be8[nt];
        y2n[(M0 + ml) * CHN + col] = f2bf(yn);
      }
    }
  }
}

// ------------------- GEMM3: y = y2n W_dec^T + b_dec (fp32 out) + maxy atomics
__global__ __launch_bounds__(256) void k_gemm3(const unsigned short* y2n,
                                               const unsigned short* wb, const float* bd,
                                               float* yout, unsigned int* maxy) {
  __shared__ __align__(16) unsigned short Ws[256 * 40];
  __shared__ __align__(16) unsigned short Asb[64 * 40];
  int tid = threadIdx.x, lane = tid & 63, wv = tid >> 6;
  int ln15 = lane & 15, hf = lane >> 4, quad = hf;
  size_t M0 = (size_t)blockIdx.x * 64;           // grid 1024
  int b = (int)(M0 >> 13);
  int mh = wv & 1, nh = wv >> 1;
  f32x4 acc[2][8];
#pragma unroll
  for (int i = 0; i < 2; ++i)
#pragma unroll
    for (int j = 0; j < 8; ++j) { acc[i][j][0]=0.f; acc[i][j][1]=0.f; acc[i][j][2]=0.f; acc[i][j][3]=0.f; }

  for (int k0 = 0; k0 < CHN; k0 += 32) {
    __syncthreads();
#pragma unroll
    for (int i = 0; i < 4; ++i) {               // stage W: 256 rows x 4 chunks
      int cch = tid + 256 * i, row = cch >> 2, h = cch & 3;
      *(uint4*)&Ws[row * 40 + h * 8] = *(const uint4*)(wb + (size_t)row * CHN + k0 + h * 8);
    }
    {                                           // stage A: 64 rows x 4 chunks
      int row = tid >> 2, h = tid & 3;
      *(uint4*)&Asb[row * 40 + h * 8] = *(const uint4*)(y2n + (M0 + row) * CHN + k0 + h * 8);
    }
    __syncthreads();
    s16x8 af[2], bfr[8];
#pragma unroll
    for (int mt = 0; mt < 2; ++mt)
      af[mt] = *(const s16x8*)&Asb[(32 * mh + 16 * mt + ln15) * 40 + hf * 8];
#pragma unroll
    for (int nt = 0; nt < 8; ++nt)
      bfr[nt] = *(const s16x8*)&Ws[(128 * nh + 16 * nt + ln15) * 40 + hf * 8];
#pragma unroll
    for (int mt = 0; mt < 2; ++mt)
#pragma unroll
      for (int nt = 0; nt < 8; ++nt)
        acc[mt][nt] = MFMA16(af[mt], bfr[nt], acc[mt][nt]);
  }
  float bd8[8];
#pragma unroll
  for (int nt = 0; nt < 8; ++nt) bd8[nt] = bd[128 * nh + 16 * nt + ln15];
#pragma unroll
  for (int mt = 0; mt < 2; ++mt)
#pragma unroll
    for (int r = 0; r < 4; ++r) {
      int ml = 32 * mh + 16 * mt + 4 * quad + r;
#pragma unroll
      for (int nt = 0; nt < 8; ++nt) {
        int col = 128 * nh + 16 * nt + ln15;
        float v = acc[mt][nt][r] + bd8[nt];
        acc[mt][nt][r] = v;
        yout[(M0 + ml) * CHN + col] = v;
      }
    }
#pragma unroll
  for (int nt = 0; nt < 8; ++nt) {
    int col = 128 * nh + 16 * nt + ln15;
    float mv = 0.f;
#pragma unroll
    for (int mt = 0; mt < 2; ++mt)
#pragma unroll
      for (int r = 0; r < 4; ++r) mv = fmaxf(mv, fabsf(acc[mt][nt][r]));
    mv = fmaxf(mv, __shfl_xor(mv, 16));
    mv = fmaxf(mv, __shfl_xor(mv, 32));
    if (quad == 0) atomicMax(&maxy[b * CHN + col], __float_as_uint(mv));
  }
}

// ------------------------------------------------------------ h = my/(mx+eps)
__global__ __launch_bounds__(256) void k_hfin(const unsigned int* maxxe,
                                              const unsigned int* maxy, float* hout) {
  int i = blockIdx.x * 256 + threadIdx.x;        // grid 8
  if (i < BSZ * CHN) {
    float mx = __uint_as_float(maxxe[i]);
    float my = __uint_as_float(maxy[i]);
    hout[i] = my / (mx + 1e-6f);
  }
}

// ---------------------------------------------------------------------------
extern "C" void kernel_launch(void* const* d_in, const int* in_sizes, int n_in,
                              void* d_out, int out_size, void* d_ws, size_t ws_size,
                              hipStream_t stream) {
  const float* x   = (const float*)d_in[0];
  const float* A   = (const float*)d_in[1];
  const float* Bp  = (const float*)d_in[2];
  const float* h0  = (const float*)d_in[3];
  const float* We  = (const float*)d_in[4];
  const float* be  = (const float*)d_in[5];
  const float* Wf  = (const float*)d_in[6];
  const float* bfc = (const float*)d_in[7];
  const float* gam = (const float*)d_in[8];
  const float* bet = (const float*)d_in[9];
  const float* Wd  = (const float*)d_in[10];
  const float* bd  = (const float*)d_in[11];

  char* ws = (char*)d_ws;
  unsigned short* y1  = (unsigned short*)(ws + 0);          // 33554432 B
  unsigned short* afr = (unsigned short*)(ws + 33554432);   //  4456448 B
  unsigned short* web = (unsigned short*)(ws + 38010880);   //   131072 B
  unsigned short* wfb = (unsigned short*)(ws + 38141952);
  unsigned short* wdb = (unsigned short*)(ws + 38273024);
  unsigned int*  maxxe = (unsigned int*)(ws + 38404096);    //     8192 B
  unsigned int*  maxy  = (unsigned int*)(ws + 38412288);    //     8192 B

  unsigned short* xeT = (unsigned short*)d_out;             // scratch: 35.8 MB
  float* yout = (float*)d_out;
  float* hout = yout + YELEMS;

  k_prep<<<768, 256, 0, stream>>>(We, Wf, Wd, web, wfb, wdb);
  k_zero<<<548, 256, 0, stream>>>(xeT, (uint4*)maxxe);
  k_kgen<<<64, 256, 0, stream>>>(A, Bp, afr);
  k_gemm1<<<1024, 256, 0, stream>>>(x, web, be, xeT, maxxe);
  k_conv<<<8192, 256, 0, stream>>>(xeT, afr, y1, h0);
  k_gemm2<<<1024, 256, 0, stream>>>(y1, wfb, bfc, xeT, gam, bet, y1);
  k_gemm3<<<1024, 256, 0, stream>>>(y1, wdb, bd, yout, maxy);
  k_hfin<<<8, 256, 0, stream>>>(maxxe, maxy, hout);
}

// Round 4
// 325.778 us; speedup vs baseline: 1.3931x; 1.1102x over previous
//
#include <hip/hip_runtime.h>
#include <math.h>

// ---------------------------------------------------------------------------
// RTF-SSM block, MI355X. FFT path replaced by:
//   K = impulse response of B(z)/A(z), truncated at 512 taps (Newton
//   power-series inversion, 9 wave-parallel doubling steps).
//   causal conv = Toeplitz-block bf16 MFMA (16x16x32), A-frags prebuilt.
//   3 GEMMs (65536x256x256) bf16 MFMA with fused bias/gelu/skip/LN/max.
// R4: GEMMs restructured: BK=64 (4 k-iters, half the barriers),
//   global_load_lds width-16 staging (no VGPR roundtrip, no staging
//   ds_writes -> bank conflicts gone), XOR-perm LDS chunk layout
//   (chunk(row,h) at row*8 + (h^(row&7))) for bank-spread frag reads,
//   gemm2 epilogue xe skip-read via dwordx2 (4 consecutive t per lane).
// ---------------------------------------------------------------------------

#define BSZ   8
#define SEQ   8192
#define CHN   256
#define ORD   64
#define STAPS 512
#define NDD   17            // d-pairs: covers d = 0..33 (taps to 543 >= 511)
#define PREPAD 544          // history prepad (>= 528 needed), 16-aligned
#define XROW  (PREPAD + SEQ) // 8736 elems per (b,c) row of xe^T
#define MTOT  (BSZ * SEQ)   // 65536
#define YELEMS (MTOT * CHN) // 16777216

typedef short s16x8 __attribute__((ext_vector_type(8)));
typedef float f32x4 __attribute__((ext_vector_type(4)));

#define MFMA16(a, b, c) __builtin_amdgcn_mfma_f32_16x16x32_bf16((a), (b), (c), 0, 0, 0)

// async global->LDS 16B: LDS dest = wave-uniform base + lane*16
__device__ __forceinline__ void gll16(const void* g, void* l) {
  __builtin_amdgcn_global_load_lds(
      (const __attribute__((address_space(1))) unsigned int*)g,
      (__attribute__((address_space(3))) unsigned int*)l, 16, 0, 0);
}

// XOR-perm chunk layout: chunk p of (row,h) stored at elems PERМ*8
#define PERMC(row, h) (((row) * 8 + ((h) ^ ((row) & 7))) * 8)

__device__ __forceinline__ unsigned short f2bf(float f) {
  unsigned u = __float_as_uint(f);
  return (unsigned short)((u + 0x7FFFu + ((u >> 16) & 1u)) >> 16);
}
__device__ __forceinline__ float bf2f(unsigned short h) {
  return __uint_as_float(((unsigned)h) << 16);
}
__device__ __forceinline__ float geluf(float x) {
  return 0.5f * x * (1.0f + erff(x * 0.70710678118654752f));
}
__device__ __forceinline__ uint4 packbf8(float4 a, float4 b) {
  uint4 r;
  r.x = (unsigned)f2bf(a.x) | ((unsigned)f2bf(a.y) << 16);
  r.y = (unsigned)f2bf(a.z) | ((unsigned)f2bf(a.w) << 16);
  r.z = (unsigned)f2bf(b.x) | ((unsigned)f2bf(b.y) << 16);
  r.w = (unsigned)f2bf(b.z) | ((unsigned)f2bf(b.w) << 16);
  return r;
}

// ---------------------------------------------------------------- weights->bf16
__global__ __launch_bounds__(256) void k_prep(const float* we, const float* wf,
                                              const float* wd, unsigned short* owe,
                                              unsigned short* owf, unsigned short* owd) {
  int i = blockIdx.x * 256 + threadIdx.x;       // grid 768 -> 196608
  int which = i >> 16, off = i & 65535;
  if (which == 0)      owe[off] = f2bf(we[off]);
  else if (which == 1) owf[off] = f2bf(wf[off]);
  else                 owd[off] = f2bf(wd[off]);
}

// ------------------------------------------------- zero prepads + max buffers
__global__ __launch_bounds__(256) void k_zero(unsigned short* xeT, uint4* maxbufs) {
  int i = blockIdx.x * 256 + threadIdx.x;       // grid 548
  uint4 z; z.x = 0; z.y = 0; z.z = 0; z.w = 0;
  if (i < 2048 * 68) {                          // 544 elems/row = 68 x 16B chunks
    int row = i / 68, cc = i % 68;
    *(uint4*)((char*)xeT + (size_t)row * (XROW * 2) + (size_t)cc * 16) = z;
  } else {
    int j = i - 2048 * 68;
    if (j < 1024) maxbufs[j] = z;               // maxxe (8KB) + maxy (8KB)
  }
}

// ---------------- K-gen: Newton inversion of A(z) + B*G conv + Toeplitz frags
__global__ __launch_bounds__(256) void k_kgen(const float* A, const float* Bp,
                                              unsigned short* afr) {
  __shared__ float Gs[4][STAPS];
  __shared__ float Et[4][64];
  __shared__ float Ac[4][65];
  __shared__ float Bb[4][64];
  __shared__ float Kb[4][STAPS];
  int lane = threadIdx.x & 63, wv = threadIdx.x >> 6;
  int c = blockIdx.x * 4 + wv;                  // grid 64
  Ac[wv][lane + 1] = A[(size_t)c * ORD + lane];
  Bb[wv][lane]     = Bp[(size_t)c * ORD + lane];
  if (lane == 0) { Ac[wv][0] = 1.f; Gs[wv][0] = 1.f; }
  __syncthreads();

  for (int n = 1; n < STAPS; n <<= 1) {
    float e = 0.f;
    int uhi = min(n + lane, 64);
    for (int u = lane + 1; u <= uhi; ++u)
      e += Ac[wv][u] * Gs[wv][n + lane - u];
    Et[wv][lane] = e;
    __syncthreads();
    int nk = (n + 63) >> 6;
    for (int k = 0; k < nk; ++k) {
      int idx = k * 64 + lane;
      if (idx < n) {
        float acc = 0.f;
        int imax = min(idx, 63);
        for (int i = 0; i <= imax; ++i)
          acc += Et[wv][i] * Gs[wv][idx - i];
        Gs[wv][n + idx] = -acc;
      }
    }
    __syncthreads();
  }

  for (int k = 0; k < 8; ++k) {
    int t = k * 64 + lane;
    float acc = 0.f;
    int jmax = min(t, 63);
    for (int j = 0; j <= jmax; ++j)
      acc += Bb[wv][j] * Gs[wv][t - j];
    Kb[wv][t] = acc;
  }
  __syncthreads();

  int m = lane & 15, quad = lane >> 4;
  for (int dd = 0; dd < NDD; ++dd) {
    unsigned short v[8];
#pragma unroll
    for (int j = 0; j < 8; ++j) {
      int k = quad * 8 + j;
      int d = 2 * dd + (k >> 4);
      int p = k & 15;
      int s = 16 * d + m - p;
      float kv = (s >= 0 && s < STAPS) ? Kb[wv][s] : 0.f;
      v[j] = f2bf(kv);
    }
    uint4 pk;
    pk.x = (unsigned)v[0] | ((unsigned)v[1] << 16);
    pk.y = (unsigned)v[2] | ((unsigned)v[3] << 16);
    pk.z = (unsigned)v[4] | ((unsigned)v[5] << 16);
    pk.w = (unsigned)v[6] | ((unsigned)v[7] << 16);
    *(uint4*)(afr + ((size_t)(c * NDD + dd) * 64 + lane) * 8) = pk;
  }
}

// --------------- GEMM1 (transposed out): xe^T[cout][t] = W_enc x^T + b_enc
// block: 256 cout x 64 t; BK=64; W via global_load_lds, x converted in VGPRs
__global__ __launch_bounds__(256) void k_gemm1(const float* x, const unsigned short* wb,
                                               const float* benc, unsigned short* xeT,
                                               unsigned int* maxxe) {
  __shared__ __align__(16) unsigned short As[256 * 64]; // W tile, perm layout
  __shared__ __align__(16) unsigned short Bs[64 * 64];  // x tile, perm layout
  int tid = threadIdx.x, lane = tid & 63, wv = tid >> 6;
  int ln15 = lane & 15, hf = lane >> 4;
  size_t t0 = (size_t)blockIdx.x * 64;          // grid 1024
  int b = (int)(t0 >> 13), tin = (int)(t0 & 8191);
  f32x4 acc[4][4];
#pragma unroll
  for (int i = 0; i < 4; ++i)
#pragma unroll
    for (int j = 0; j < 4; ++j) { acc[i][j][0]=0.f; acc[i][j][1]=0.f; acc[i][j][2]=0.f; acc[i][j][3]=0.f; }

  for (int k0 = 0; k0 < CHN; k0 += 64) {
    __syncthreads();
    // W: 2048 chunks via global_load_lds; wave wv: 8 instrs of 64 chunks
#pragma unroll
    for (int i = 0; i < 8; ++i) {
      int p = 512 * wv + 64 * i + lane;
      int row = p >> 3, h = (p & 7) ^ (row & 7);
      gll16(wb + (size_t)row * CHN + k0 + h * 8, &As[(512 * wv + 64 * i) * 8]);
    }
    {  // x: 64x64 fp32->bf16, 2 chunks/thread
      int row = tid >> 2, hb = (tid & 3) * 2;
      const float* src = x + (t0 + row) * CHN + k0 + hb * 8;
      float4 f0 = *(const float4*)src;
      float4 f1 = *(const float4*)(src + 4);
      float4 f2 = *(const float4*)(src + 8);
      float4 f3 = *(const float4*)(src + 12);
      *(uint4*)&Bs[PERMC(row, hb)]     = packbf8(f0, f1);
      *(uint4*)&Bs[PERMC(row, hb + 1)] = packbf8(f2, f3);
    }
    __syncthreads();
#pragma unroll
    for (int ks = 0; ks < 2; ++ks) {
      s16x8 af[4], bfr[4];
#pragma unroll
      for (int mt = 0; mt < 4; ++mt) {
        int row = 64 * wv + 16 * mt + ln15;
        af[mt] = *(const s16x8*)&As[PERMC(row, ks * 4 + hf)];
      }
#pragma unroll
      for (int nt = 0; nt < 4; ++nt) {
        int row = 16 * nt + ln15;
        bfr[nt] = *(const s16x8*)&Bs[PERMC(row, ks * 4 + hf)];
      }
#pragma unroll
      for (int mt = 0; mt < 4; ++mt)
#pragma unroll
        for (int nt = 0; nt < 4; ++nt)
          acc[mt][nt] = MFMA16(af[mt], bfr[nt], acc[mt][nt]);
    }
  }
  // epilogue: D[m=cout][n=t]; col=lane&15=t, row=quad*4+r
  int quad = hf;
#pragma unroll
  for (int mt = 0; mt < 4; ++mt) {
#pragma unroll
    for (int r = 0; r < 4; ++r) {
      int row = 64 * wv + 16 * mt + 4 * quad + r;
      float bias = benc[row];
      float mv = 0.f;
#pragma unroll
      for (int nt = 0; nt < 4; ++nt) {
        float v = acc[mt][nt][r] + bias;
        int t = tin + 16 * nt + ln15;
        xeT[(size_t)(b * CHN + row) * XROW + PREPAD + t] = f2bf(v);
        mv = fmaxf(mv, fabsf(v));
      }
      mv = fmaxf(mv, __shfl_xor(mv, 1)); mv = fmaxf(mv, __shfl_xor(mv, 2));
      mv = fmaxf(mv, __shfl_xor(mv, 4)); mv = fmaxf(mv, __shfl_xor(mv, 8));
      if (ln15 == 0) atomicMax(&maxxe[b * CHN + row], __float_as_uint(mv));
    }
  }
}

// ------------- conv: y1[t][c] = gelu(FIR(xe) + h0*xe); block = 8 ch x 256 t
__global__ __launch_bounds__(256) void k_conv(const unsigned short* xeT,
                                              const unsigned short* afr,
                                              unsigned short* y1, const float* h0p) {
  __shared__ __align__(16) unsigned short xet[8 * 1024]; // 8 rows x 128 chunks (swizzled)
  __shared__ __align__(16) unsigned short bnc[8 * 256];  // transpose bounce
  int tid = threadIdx.x;
  int idx = blockIdx.x;                          // grid 8192 = 8b x 32cg x 32tg
  int tg = idx & 31, cg = (idx >> 5) & 31, b = idx >> 10;
  int c0 = cg * 8, t0 = tg * 256;
  for (int i = tid; i < 800; i += 256) {
    int row = i / 100, cc = i % 100;
    uint4 v = *(const uint4*)(xeT + (size_t)(b * CHN + c0 + row) * XROW + t0 + cc * 8);
    int sw = cc ^ ((cc >> 3) & 7);
    *(uint4*)&xet[row * 1024 + sw * 8] = v;
  }
  __syncthreads();
  int lane = tid & 63, wv = tid >> 6;
  int n = lane & 15, quad = lane >> 4;
  int qc = quad - ((quad >> 1) << 2);            // 0,1,-2,-1
  float h0 = h0p[0];
#pragma unroll
  for (int ci = 0; ci < 2; ++ci) {
    int cl = wv * 2 + ci;
    int c = c0 + cl;
    f32x4 acc; acc[0]=0.f; acc[1]=0.f; acc[2]=0.f; acc[3]=0.f;
    const unsigned short* ap = afr + (size_t)c * (NDD * 512) + (size_t)lane * 8;
#pragma unroll 4
    for (int dd = 0; dd < NDD; ++dd) {
      s16x8 a = *(const s16x8*)(ap + (size_t)dd * 512);
      int cc = 2 * n - 4 * dd + 68 + qc;
      int sw = cc ^ ((cc >> 3) & 7);
      s16x8 bfr = *(const s16x8*)&xet[cl * 1024 + sw * 8];
      acc = MFMA16(a, bfr, acc);
    }
#pragma unroll
    for (int r = 0; r < 4; ++r) {
      int tl = 16 * n + 4 * quad + r;
      int e = PREPAD + tl;
      int ch = e >> 3, sw = ch ^ ((ch >> 3) & 7);
      float xv = bf2f(xet[cl * 1024 + sw * 8 + (e & 7)]);
      float v = acc[r] + h0 * xv;
      bnc[cl * 256 + tl] = f2bf(geluf(v));
    }
  }
  __syncthreads();
  {                                              // coalesced 16B stores: 8 ch per t
    int tl = tid;
    uint4 pk;
    pk.x = (unsigned)bnc[0 * 256 + tl] | ((unsigned)bnc[1 * 256 + tl] << 16);
    pk.y = (unsigned)bnc[2 * 256 + tl] | ((unsigned)bnc[3 * 256 + tl] << 16);
    pk.z = (unsigned)bnc[4 * 256 + tl] | ((unsigned)bnc[5 * 256 + tl] << 16);
    pk.w = (unsigned)bnc[6 * 256 + tl] | ((unsigned)bnc[7 * 256 + tl] << 16);
    *(uint4*)(y1 + (size_t)(b * SEQ + t0 + tl) * CHN + c0) = pk;
  }
}

// ------ GEMM2: y2n = LN(gelu(y1 W_fc^T + b_fc) + xe)*gamma+beta, in-place y1
// block: 64 t x 256 cout; BK=64; full global_load_lds staging
__global__ __launch_bounds__(256) void k_gemm2(const unsigned short* y1,
                                               const unsigned short* wb, const float* bfc,
                                               const unsigned short* xeT, const float* gam,
                                               const float* bet, unsigned short* y2n) {
  __shared__ __align__(16) unsigned short Ws[256 * 64];
  __shared__ __align__(16) unsigned short Asb[64 * 64];
  __shared__ float pl[64][2][2];
  int tid = threadIdx.x, lane = tid & 63, wv = tid >> 6;
  int ln15 = lane & 15, hf = lane >> 4, quad = hf;
  size_t M0 = (size_t)blockIdx.x * 64;           // grid 1024
  int b = (int)(M0 >> 13), tin = (int)(M0 & 8191);
  int mh = wv & 1, nh = wv >> 1;
  f32x4 acc[2][8];
#pragma unroll
  for (int i = 0; i < 2; ++i)
#pragma unroll
    for (int j = 0; j < 8; ++j) { acc[i][j][0]=0.f; acc[i][j][1]=0.f; acc[i][j][2]=0.f; acc[i][j][3]=0.f; }

  for (int k0 = 0; k0 < CHN; k0 += 64) {
    __syncthreads();
#pragma unroll
    for (int i = 0; i < 8; ++i) {               // W: 2048 chunks
      int p = 512 * wv + 64 * i + lane;
      int row = p >> 3, h = (p & 7) ^ (row & 7);
      gll16(wb + (size_t)row * CHN + k0 + h * 8, &Ws[(512 * wv + 64 * i) * 8]);
    }
#pragma unroll
    for (int i = 0; i < 2; ++i) {               // A: 512 chunks
      int p = 128 * wv + 64 * i + lane;
      int row = p >> 3, h = (p & 7) ^ (row & 7);
      gll16(y1 + (M0 + row) * CHN + k0 + h * 8, &Asb[(128 * wv + 64 * i) * 8]);
    }
    __syncthreads();
#pragma unroll
    for (int ks = 0; ks < 2; ++ks) {
      s16x8 af[2], bfr[8];
#pragma unroll
      for (int mt = 0; mt < 2; ++mt) {
        int row = 32 * mh + 16 * mt + ln15;
        af[mt] = *(const s16x8*)&Asb[PERMC(row, ks * 4 + hf)];
      }
#pragma unroll
      for (int nt = 0; nt < 8; ++nt) {
        int row = 128 * nh + 16 * nt + ln15;
        bfr[nt] = *(const s16x8*)&Ws[PERMC(row, ks * 4 + hf)];
      }
#pragma unroll
      for (int mt = 0; mt < 2; ++mt)
#pragma unroll
        for (int nt = 0; nt < 8; ++nt)
          acc[mt][nt] = MFMA16(af[mt], bfr[nt], acc[mt][nt]);
    }
  }
  float g8[8], be8[8], bf8[8];
#pragma unroll
  for (int nt = 0; nt < 8; ++nt) {
    int col = 128 * nh + 16 * nt + ln15;
    g8[nt] = gam[col]; be8[nt] = bet[col]; bf8[nt] = bfc[col];
  }
#pragma unroll
  for (int mt = 0; mt < 2; ++mt) {
    int mlb = 32 * mh + 16 * mt + 4 * quad;
    uint2 xv2[8];
#pragma unroll
    for (int nt = 0; nt < 8; ++nt) {            // xe skip: 4 consecutive t per lane
      int col = 128 * nh + 16 * nt + ln15;
      xv2[nt] = *(const uint2*)(xeT + (size_t)(b * CHN + col) * XROW + PREPAD + tin + mlb);
    }
#pragma unroll
    for (int r = 0; r < 4; ++r) {
      int ml = mlb + r;
      float s1 = 0.f, s2 = 0.f;
#pragma unroll
      for (int nt = 0; nt < 8; ++nt) {
        float t2 = acc[mt][nt][r] + bf8[nt];
        float xv = bf2f(((const unsigned short*)&xv2[nt])[r]);
        float y2 = geluf(t2) + xv;
        acc[mt][nt][r] = y2;
        s1 += y2; s2 += y2 * y2;
      }
      s1 += __shfl_xor(s1, 1); s2 += __shfl_xor(s2, 1);
      s1 += __shfl_xor(s1, 2); s2 += __shfl_xor(s2, 2);
      s1 += __shfl_xor(s1, 4); s2 += __shfl_xor(s2, 4);
      s1 += __shfl_xor(s1, 8); s2 += __shfl_xor(s2, 8);
      if (ln15 == 0) { pl[ml][nh][0] = s1; pl[ml][nh][1] = s2; }
    }
  }
  __syncthreads();
#pragma unroll
  for (int mt = 0; mt < 2; ++mt) {
#pragma unroll
    for (int r = 0; r < 4; ++r) {
      int ml = 32 * mh + 16 * mt + 4 * quad + r;
      float s1 = pl[ml][0][0] + pl[ml][1][0];
      float s2 = pl[ml][0][1] + pl[ml][1][1];
      float mu = s1 * (1.f / 256.f);
      float var = s2 * (1.f / 256.f) - mu * mu;
      float ri = rsqrtf(var + 1e-5f);
#pragma unroll
      for (int nt = 0; nt < 8; ++nt) {
        int col = 128 * nh + 16 * nt + ln15;
        float yn = (acc[mt][nt][r] - mu) * ri * g8[nt] + be8[nt];
        y2n[(M0 + ml) * CHN + col] = f2bf(yn);
      }
    }
  }
}

// ------------------- GEMM3: y = y2n W_dec^T + b_dec (fp32 out) + maxy atomics
__global__ __launch_bounds__(256) void k_gemm3(const unsigned short* y2n,
                                               const unsigned short* wb, const float* bd,
                                               float* yout, unsigned int* maxy) {
  __shared__ __align__(16) unsigned short Ws[256 * 64];
  __shared__ __align__(16) unsigned short Asb[64 * 64];
  int tid = threadIdx.x, lane = tid & 63, wv = tid >> 6;
  int ln15 = lane & 15, hf = lane >> 4, quad = hf;
  size_t M0 = (size_t)blockIdx.x * 64;           // grid 1024
  int b = (int)(M0 >> 13);
  int mh = wv & 1, nh = wv >> 1;
  f32x4 acc[2][8];
#pragma unroll
  for (int i = 0; i < 2; ++i)
#pragma unroll
    for (int j = 0; j < 8; ++j) { acc[i][j][0]=0.f; acc[i][j][1]=0.f; acc[i][j][2]=0.f; acc[i][j][3]=0.f; }

  for (int k0 = 0; k0 < CHN; k0 += 64) {
    __syncthreads();
#pragma unroll
    for (int i = 0; i < 8; ++i) {               // W: 2048 chunks
      int p = 512 * wv + 64 * i + lane;
      int row = p >> 3, h = (p & 7) ^ (row & 7);
      gll16(wb + (size_t)row * CHN + k0 + h * 8, &Ws[(512 * wv + 64 * i) * 8]);
    }
#pragma unroll
    for (int i = 0; i < 2; ++i) {               // A: 512 chunks
      int p = 128 * wv + 64 * i + lane;
      int row = p >> 3, h = (p & 7) ^ (row & 7);
      gll16(y2n + (M0 + row) * CHN + k0 + h * 8, &Asb[(128 * wv + 64 * i) * 8]);
    }
    __syncthreads();
#pragma unroll
    for (int ks = 0; ks < 2; ++ks) {
      s16x8 af[2], bfr[8];
#pragma unroll
      for (int mt = 0; mt < 2; ++mt) {
        int row = 32 * mh + 16 * mt + ln15;
        af[mt] = *(const s16x8*)&Asb[PERMC(row, ks * 4 + hf)];
      }
#pragma unroll
      for (int nt = 0; nt < 8; ++nt) {
        int row = 128 * nh + 16 * nt + ln15;
        bfr[nt] = *(const s16x8*)&Ws[PERMC(row, ks * 4 + hf)];
      }
#pragma unroll
      for (int mt = 0; mt < 2; ++mt)
#pragma unroll
        for (int nt = 0; nt < 8; ++nt)
          acc[mt][nt] = MFMA16(af[mt], bfr[nt], acc[mt][nt]);
    }
  }
  float bd8[8];
#pragma unroll
  for (int nt = 0; nt < 8; ++nt) bd8[nt] = bd[128 * nh + 16 * nt + ln15];
#pragma unroll
  for (int mt = 0; mt < 2; ++mt)
#pragma unroll
    for (int r = 0; r < 4; ++r) {
      int ml = 32 * mh + 16 * mt + 4 * quad + r;
#pragma unroll
      for (int nt = 0; nt < 8; ++nt) {
        int col = 128 * nh + 16 * nt + ln15;
        float v = acc[mt][nt][r] + bd8[nt];
        acc[mt][nt][r] = v;
        yout[(M0 + ml) * CHN + col] = v;
      }
    }
#pragma unroll
  for (int nt = 0; nt < 8; ++nt) {
    int col = 128 * nh + 16 * nt + ln15;
    float mv = 0.f;
#pragma unroll
    for (int mt = 0; mt < 2; ++mt)
#pragma unroll
      for (int r = 0; r < 4; ++r) mv = fmaxf(mv, fabsf(acc[mt][nt][r]));
    mv = fmaxf(mv, __shfl_xor(mv, 16));
    mv = fmaxf(mv, __shfl_xor(mv, 32));
    if (quad == 0) atomicMax(&maxy[b * CHN + col], __float_as_uint(mv));
  }
}

// ------------------------------------------------------------ h = my/(mx+eps)
__global__ __launch_bounds__(256) void k_hfin(const unsigned int* maxxe,
                                              const unsigned int* maxy, float* hout) {
  int i = blockIdx.x * 256 + threadIdx.x;        // grid 8
  if (i < BSZ * CHN) {
    float mx = __uint_as_float(maxxe[i]);
    float my = __uint_as_float(maxy[i]);
    hout[i] = my / (mx + 1e-6f);
  }
}

// ---------------------------------------------------------------------------
extern "C" void kernel_launch(void* const* d_in, const int* in_sizes, int n_in,
                              void* d_out, int out_size, void* d_ws, size_t ws_size,
                              hipStream_t stream) {
  const float* x   = (const float*)d_in[0];
  const float* A   = (const float*)d_in[1];
  const float* Bp  = (const float*)d_in[2];
  const float* h0  = (const float*)d_in[3];
  const float* We  = (const float*)d_in[4];
  const float* be  = (const float*)d_in[5];
  const float* Wf  = (const float*)d_in[6];
  const float* bfc = (const float*)d_in[7];
  const float* gam = (const float*)d_in[8];
  const float* bet = (const float*)d_in[9];
  const float* Wd  = (const float*)d_in[10];
  const float* bd  = (const float*)d_in[11];

  char* ws = (char*)d_ws;
  unsigned short* y1  = (unsigned short*)(ws + 0);          // 33554432 B
  unsigned short* afr = (unsigned short*)(ws + 33554432);   //  4456448 B
  unsigned short* web = (unsigned short*)(ws + 38010880);   //   131072 B
  unsigned short* wfb = (unsigned short*)(ws + 38141952);
  unsigned short* wdb = (unsigned short*)(ws + 38273024);
  unsigned int*  maxxe = (unsigned int*)(ws + 38404096);    //     8192 B
  unsigned int*  maxy  = (unsigned int*)(ws + 38412288);    //     8192 B

  unsigned short* xeT = (unsigned short*)d_out;             // scratch: 35.8 MB
  float* yout = (float*)d_out;
  float* hout = yout + YELEMS;

  k_prep<<<768, 256, 0, stream>>>(We, Wf, Wd, web, wfb, wdb);
  k_zero<<<548, 256, 0, stream>>>(xeT, (uint4*)maxxe);
  k_kgen<<<64, 256, 0, stream>>>(A, Bp, afr);
  k_gemm1<<<1024, 256, 0, stream>>>(x, web, be, xeT, maxxe);
  k_conv<<<8192, 256, 0, stream>>>(xeT, afr, y1, h0);
  k_gemm2<<<1024, 256, 0, stream>>>(y1, wfb, bfc, xeT, gam, bet, y1);
  k_gemm3<<<1024, 256, 0, stream>>>(y1, wdb, bd, yout, maxy);
  k_hfin<<<8, 256, 0, stream>>>(maxxe, maxy, hout);
}

// Round 5
// 310.783 us; speedup vs baseline: 1.4603x; 1.0482x over previous
//
#include <hip/hip_runtime.h>
#include <math.h>

// ---------------------------------------------------------------------------
// RTF-SSM block, MI355X. FFT path replaced by:
//   K = impulse response of B(z)/A(z), truncated at 512 taps (Newton
//   power-series inversion, 9 wave-parallel doubling steps).
//   causal conv = Toeplitz-block bf16 MFMA (16x16x32), A-frags prebuilt.
//   3 GEMMs (65536x256x256) bf16 MFMA with fused bias/gelu/skip/LN/max.
// R5: k_conv restructured: t-tile 2048 (halo redundancy 3.1x -> 1.27x),
//   wave-owns-channel with 17 A-frags held in VGPRs (afr re-reads 8x down,
//   no LDS a-frag traffic), xe staged via global_load_lds w/ XOR-perm
//   expressed as per-lane global offsets, 2 barriers/block (was 16),
//   dual MFMA accumulation chains.
// ---------------------------------------------------------------------------

#define BSZ   8
#define SEQ   8192
#define CHN   256
#define ORD   64
#define STAPS 512
#define NDD   17            // d-pairs: covers d = 0..33 (taps to 543 >= 511)
#define PREPAD 544          // history prepad (>= 528 needed), 16-aligned
#define XROW  (PREPAD + SEQ) // 8736 elems per (b,c) row of xe^T
#define MTOT  (BSZ * SEQ)   // 65536
#define YELEMS (MTOT * CHN) // 16777216

#define CT     2048         // conv t-tile per block
#define CROWE  3072         // conv LDS row stride (384 chunks)

typedef short s16x8 __attribute__((ext_vector_type(8)));
typedef float f32x4 __attribute__((ext_vector_type(4)));

#define MFMA16(a, b, c) __builtin_amdgcn_mfma_f32_16x16x32_bf16((a), (b), (c), 0, 0, 0)

// async global->LDS 16B: LDS dest = wave-uniform base + lane*16
__device__ __forceinline__ void gll16(const void* g, void* l) {
  __builtin_amdgcn_global_load_lds(
      (const __attribute__((address_space(1))) unsigned int*)g,
      (__attribute__((address_space(3))) unsigned int*)l, 16, 0, 0);
}

// XOR-perm chunk layout: chunk p of (row,h) stored at elems PERMC
#define PERMC(row, h) (((row) * 8 + ((h) ^ ((row) & 7))) * 8)

__device__ __forceinline__ unsigned short f2bf(float f) {
  unsigned u = __float_as_uint(f);
  return (unsigned short)((u + 0x7FFFu + ((u >> 16) & 1u)) >> 16);
}
__device__ __forceinline__ float bf2f(unsigned short h) {
  return __uint_as_float(((unsigned)h) << 16);
}
__device__ __forceinline__ float geluf(float x) {
  return 0.5f * x * (1.0f + erff(x * 0.70710678118654752f));
}
__device__ __forceinline__ uint4 packbf8(float4 a, float4 b) {
  uint4 r;
  r.x = (unsigned)f2bf(a.x) | ((unsigned)f2bf(a.y) << 16);
  r.y = (unsigned)f2bf(a.z) | ((unsigned)f2bf(a.w) << 16);
  r.z = (unsigned)f2bf(b.x) | ((unsigned)f2bf(b.y) << 16);
  r.w = (unsigned)f2bf(b.z) | ((unsigned)f2bf(b.w) << 16);
  return r;
}

// ---------------------------------------------------------------- weights->bf16
__global__ __launch_bounds__(256) void k_prep(const float* we, const float* wf,
                                              const float* wd, unsigned short* owe,
                                              unsigned short* owf, unsigned short* owd) {
  int i = blockIdx.x * 256 + threadIdx.x;       // grid 768 -> 196608
  int which = i >> 16, off = i & 65535;
  if (which == 0)      owe[off] = f2bf(we[off]);
  else if (which == 1) owf[off] = f2bf(wf[off]);
  else                 owd[off] = f2bf(wd[off]);
}

// ------------------------------------------------- zero prepads + max buffers
__global__ __launch_bounds__(256) void k_zero(unsigned short* xeT, uint4* maxbufs) {
  int i = blockIdx.x * 256 + threadIdx.x;       // grid 548
  uint4 z; z.x = 0; z.y = 0; z.z = 0; z.w = 0;
  if (i < 2048 * 68) {                          // 544 elems/row = 68 x 16B chunks
    int row = i / 68, cc = i % 68;
    *(uint4*)((char*)xeT + (size_t)row * (XROW * 2) + (size_t)cc * 16) = z;
  } else {
    int j = i - 2048 * 68;
    if (j < 1024) maxbufs[j] = z;               // maxxe (8KB) + maxy (8KB)
  }
}

// ---------------- K-gen: Newton inversion of A(z) + B*G conv + Toeplitz frags
__global__ __launch_bounds__(256) void k_kgen(const float* A, const float* Bp,
                                              unsigned short* afr) {
  __shared__ float Gs[4][STAPS];
  __shared__ float Et[4][64];
  __shared__ float Ac[4][65];
  __shared__ float Bb[4][64];
  __shared__ float Kb[4][STAPS];
  int lane = threadIdx.x & 63, wv = threadIdx.x >> 6;
  int c = blockIdx.x * 4 + wv;                  // grid 64
  Ac[wv][lane + 1] = A[(size_t)c * ORD + lane];
  Bb[wv][lane]     = Bp[(size_t)c * ORD + lane];
  if (lane == 0) { Ac[wv][0] = 1.f; Gs[wv][0] = 1.f; }
  __syncthreads();

  for (int n = 1; n < STAPS; n <<= 1) {
    float e = 0.f;
    int uhi = min(n + lane, 64);
    for (int u = lane + 1; u <= uhi; ++u)
      e += Ac[wv][u] * Gs[wv][n + lane - u];
    Et[wv][lane] = e;
    __syncthreads();
    int nk = (n + 63) >> 6;
    for (int k = 0; k < nk; ++k) {
      int idx = k * 64 + lane;
      if (idx < n) {
        float acc = 0.f;
        int imax = min(idx, 63);
        for (int i = 0; i <= imax; ++i)
          acc += Et[wv][i] * Gs[wv][idx - i];
        Gs[wv][n + idx] = -acc;
      }
    }
    __syncthreads();
  }

  for (int k = 0; k < 8; ++k) {
    int t = k * 64 + lane;
    float acc = 0.f;
    int jmax = min(t, 63);
    for (int j = 0; j <= jmax; ++j)
      acc += Bb[wv][j] * Gs[wv][t - j];
    Kb[wv][t] = acc;
  }
  __syncthreads();

  int m = lane & 15, quad = lane >> 4;
  for (int dd = 0; dd < NDD; ++dd) {
    unsigned short v[8];
#pragma unroll
    for (int j = 0; j < 8; ++j) {
      int k = quad * 8 + j;
      int d = 2 * dd + (k >> 4);
      int p = k & 15;
      int s = 16 * d + m - p;
      float kv = (s >= 0 && s < STAPS) ? Kb[wv][s] : 0.f;
      v[j] = f2bf(kv);
    }
    uint4 pk;
    pk.x = (unsigned)v[0] | ((unsigned)v[1] << 16);
    pk.y = (unsigned)v[2] | ((unsigned)v[3] << 16);
    pk.z = (unsigned)v[4] | ((unsigned)v[5] << 16);
    pk.w = (unsigned)v[6] | ((unsigned)v[7] << 16);
    *(uint4*)(afr + ((size_t)(c * NDD + dd) * 64 + lane) * 8) = pk;
  }
}

// --------------- GEMM1 (transposed out): xe^T[cout][t] = W_enc x^T + b_enc
// block: 256 cout x 64 t; BK=64; W via global_load_lds, x converted in VGPRs
__global__ __launch_bounds__(256) void k_gemm1(const float* x, const unsigned short* wb,
                                               const float* benc, unsigned short* xeT,
                                               unsigned int* maxxe) {
  __shared__ __align__(16) unsigned short As[256 * 64]; // W tile, perm layout
  __shared__ __align__(16) unsigned short Bs[64 * 64];  // x tile, perm layout
  int tid = threadIdx.x, lane = tid & 63, wv = tid >> 6;
  int ln15 = lane & 15, hf = lane >> 4;
  size_t t0 = (size_t)blockIdx.x * 64;          // grid 1024
  int b = (int)(t0 >> 13), tin = (int)(t0 & 8191);
  f32x4 acc[4][4];
#pragma unroll
  for (int i = 0; i < 4; ++i)
#pragma unroll
    for (int j = 0; j < 4; ++j) { acc[i][j][0]=0.f; acc[i][j][1]=0.f; acc[i][j][2]=0.f; acc[i][j][3]=0.f; }

  for (int k0 = 0; k0 < CHN; k0 += 64) {
    __syncthreads();
#pragma unroll
    for (int i = 0; i < 8; ++i) {
      int p = 512 * wv + 64 * i + lane;
      int row = p >> 3, h = (p & 7) ^ (row & 7);
      gll16(wb + (size_t)row * CHN + k0 + h * 8, &As[(512 * wv + 64 * i) * 8]);
    }
    {  // x: 64x64 fp32->bf16, 2 chunks/thread
      int row = tid >> 2, hb = (tid & 3) * 2;
      const float* src = x + (t0 + row) * CHN + k0 + hb * 8;
      float4 f0 = *(const float4*)src;
      float4 f1 = *(const float4*)(src + 4);
      float4 f2 = *(const float4*)(src + 8);
      float4 f3 = *(const float4*)(src + 12);
      *(uint4*)&Bs[PERMC(row, hb)]     = packbf8(f0, f1);
      *(uint4*)&Bs[PERMC(row, hb + 1)] = packbf8(f2, f3);
    }
    __syncthreads();
#pragma unroll
    for (int ks = 0; ks < 2; ++ks) {
      s16x8 af[4], bfr[4];
#pragma unroll
      for (int mt = 0; mt < 4; ++mt) {
        int row = 64 * wv + 16 * mt + ln15;
        af[mt] = *(const s16x8*)&As[PERMC(row, ks * 4 + hf)];
      }
#pragma unroll
      for (int nt = 0; nt < 4; ++nt) {
        int row = 16 * nt + ln15;
        bfr[nt] = *(const s16x8*)&Bs[PERMC(row, ks * 4 + hf)];
      }
#pragma unroll
      for (int mt = 0; mt < 4; ++mt)
#pragma unroll
        for (int nt = 0; nt < 4; ++nt)
          acc[mt][nt] = MFMA16(af[mt], bfr[nt], acc[mt][nt]);
    }
  }
  // epilogue: D[m=cout][n=t]; col=lane&15=t, row=quad*4+r
  int quad = hf;
#pragma unroll
  for (int mt = 0; mt < 4; ++mt) {
#pragma unroll
    for (int r = 0; r < 4; ++r) {
      int row = 64 * wv + 16 * mt + 4 * quad + r;
      float bias = benc[row];
      float mv = 0.f;
#pragma unroll
      for (int nt = 0; nt < 4; ++nt) {
        float v = acc[mt][nt][r] + bias;
        int t = tin + 16 * nt + ln15;
        xeT[(size_t)(b * CHN + row) * XROW + PREPAD + t] = f2bf(v);
        mv = fmaxf(mv, fabsf(v));
      }
      mv = fmaxf(mv, __shfl_xor(mv, 1)); mv = fmaxf(mv, __shfl_xor(mv, 2));
      mv = fmaxf(mv, __shfl_xor(mv, 4)); mv = fmaxf(mv, __shfl_xor(mv, 8));
      if (ln15 == 0) atomicMax(&maxxe[b * CHN + row], __float_as_uint(mv));
    }
  }
}

// ------------- conv: y1[t][c] = gelu(FIR(xe) + h0*xe)
// block = 4 ch x 2048 t; wave owns 1 channel; A-frags in VGPRs.
__global__ __launch_bounds__(256) void k_conv(const unsigned short* xeT,
                                              const unsigned short* afr,
                                              unsigned short* y1, const float* h0p) {
  __shared__ __align__(16) unsigned short xet[4 * CROWE]; // 4 rows x 384 chunks
  __shared__ __align__(16) unsigned short bnc[4 * CT];    // transpose bounce
  int tid = threadIdx.x, lane = tid & 63, wv = tid >> 6;
  int idx = blockIdx.x;                          // grid 2048 = 8b x 64cg x 4tg
  int tg = idx & 3, cg = (idx >> 2) & 63, b = idx >> 8;
  int c0 = cg * 4, t0 = tg * CT;
  int c = c0 + wv;

  // a-frags into registers (17 x 16B coalesced loads)
  s16x8 afrg[NDD];
  {
    const unsigned short* ap = afr + (size_t)c * (NDD * 512) + (size_t)lane * 8;
#pragma unroll
    for (int dd = 0; dd < NDD; ++dd)
      afrg[dd] = *(const s16x8*)(ap + (size_t)dd * 512);
  }
  // stage own channel's row [t0-544, t0+2048+..) via global_load_lds;
  // LDS slot s holds global chunk s^((s>>3)&7) (involution), so read-side
  // swizzle sw = cc^((cc>>3)&7) finds chunk cc.
  {
    int lp = lane ^ ((lane >> 3) & 7);
    const unsigned short* gbase = xeT + (size_t)(b * CHN + c) * XROW + t0;
    unsigned short* lbase = &xet[wv * CROWE];
#pragma unroll
    for (int k = 0; k < 6; ++k)
      gll16(gbase + (size_t)(64 * k + lp) * 8, &lbase[k * 64 * 8]);
  }
  float h0 = h0p[0];
  __syncthreads();

  int n = lane & 15, quad = lane >> 4;
  int qc = quad - ((quad >> 1) << 2);            // 0,1,-2,-1
  const unsigned short* xrow = &xet[wv * CROWE];
#pragma unroll 1
  for (int s = 0; s < 8; ++s) {
    f32x4 a0, a1;
    a0[0]=0.f; a0[1]=0.f; a0[2]=0.f; a0[3]=0.f;
    a1[0]=0.f; a1[1]=0.f; a1[2]=0.f; a1[3]=0.f;
    int cbase = 2 * n + qc + 68 + 32 * s;
#pragma unroll
    for (int dd = 0; dd < 16; dd += 2) {
      int cc0 = cbase - 4 * dd, cc1 = cc0 - 4;
      int sw0 = cc0 ^ ((cc0 >> 3) & 7), sw1 = cc1 ^ ((cc1 >> 3) & 7);
      a0 = MFMA16(afrg[dd],     *(const s16x8*)&xrow[sw0 * 8], a0);
      a1 = MFMA16(afrg[dd + 1], *(const s16x8*)&xrow[sw1 * 8], a1);
    }
    {
      int cc = cbase - 64, sw = cc ^ ((cc >> 3) & 7);
      a0 = MFMA16(afrg[16], *(const s16x8*)&xrow[sw * 8], a0);
    }
    // epilogue: tl = 256s + 16n + 4q + r; pack 4 bf16 -> one b64 LDS write
    unsigned short o[4];
#pragma unroll
    for (int r = 0; r < 4; ++r) {
      int tl = 256 * s + 16 * n + 4 * quad + r;
      int e = PREPAD + tl;
      int ch = e >> 3, sw2 = ch ^ ((ch >> 3) & 7);
      float xv = bf2f(xrow[sw2 * 8 + (e & 7)]);
      float v = (a0[r] + a1[r]) + h0 * xv;
      o[r] = f2bf(geluf(v));
    }
    uint2 pw;
    pw.x = (unsigned)o[0] | ((unsigned)o[1] << 16);
    pw.y = (unsigned)o[2] | ((unsigned)o[3] << 16);
    *(uint2*)&bnc[wv * CT + 256 * s + 16 * n + 4 * quad] = pw;
  }
  __syncthreads();
  // store: 4 ch per t as uint2, 8 rounds
  {
    const size_t obase = (size_t)(b * SEQ + t0) * CHN + c0;
#pragma unroll
    for (int s = 0; s < 8; ++s) {
      int tl = 256 * s + tid;
      uint2 pk;
      pk.x = (unsigned)bnc[tl] | ((unsigned)bnc[CT + tl] << 16);
      pk.y = (unsigned)bnc[2 * CT + tl] | ((unsigned)bnc[3 * CT + tl] << 16);
      *(uint2*)(y1 + obase + (size_t)tl * CHN) = pk;
    }
  }
}

// ------ GEMM2: y2n = LN(gelu(y1 W_fc^T + b_fc) + xe)*gamma+beta, in-place y1
// block: 64 t x 256 cout; BK=64; full global_load_lds staging
__global__ __launch_bounds__(256) void k_gemm2(const unsigned short* y1,
                                               const unsigned short* wb, const float* bfc,
                                               const unsigned short* xeT, const float* gam,
                                               const float* bet, unsigned short* y2n) {
  __shared__ __align__(16) unsigned short Ws[256 * 64];
  __shared__ __align__(16) unsigned short Asb[64 * 64];
  __shared__ float pl[64][2][2];
  int tid = threadIdx.x, lane = tid & 63, wv = tid >> 6;
  int ln15 = lane & 15, hf = lane >> 4, quad = hf;
  size_t M0 = (size_t)blockIdx.x * 64;           // grid 1024
  int b = (int)(M0 >> 13), tin = (int)(M0 & 8191);
  int mh = wv & 1, nh = wv >> 1;
  f32x4 acc[2][8];
#pragma unroll
  for (int i = 0; i < 2; ++i)
#pragma unroll
    for (int j = 0; j < 8; ++j) { acc[i][j][0]=0.f; acc[i][j][1]=0.f; acc[i][j][2]=0.f; acc[i][j][3]=0.f; }

  for (int k0 = 0; k0 < CHN; k0 += 64) {
    __syncthreads();
#pragma unroll
    for (int i = 0; i < 8; ++i) {               // W: 2048 chunks
      int p = 512 * wv + 64 * i + lane;
      int row = p >> 3, h = (p & 7) ^ (row & 7);
      gll16(wb + (size_t)row * CHN + k0 + h * 8, &Ws[(512 * wv + 64 * i) * 8]);
    }
#pragma unroll
    for (int i = 0; i < 2; ++i) {               // A: 512 chunks
      int p = 128 * wv + 64 * i + lane;
      int row = p >> 3, h = (p & 7) ^ (row & 7);
      gll16(y1 + (M0 + row) * CHN + k0 + h * 8, &Asb[(128 * wv + 64 * i) * 8]);
    }
    __syncthreads();
#pragma unroll
    for (int ks = 0; ks < 2; ++ks) {
      s16x8 af[2], bfr[8];
#pragma unroll
      for (int mt = 0; mt < 2; ++mt) {
        int row = 32 * mh + 16 * mt + ln15;
        af[mt] = *(const s16x8*)&Asb[PERMC(row, ks * 4 + hf)];
      }
#pragma unroll
      for (int nt = 0; nt < 8; ++nt) {
        int row = 128 * nh + 16 * nt + ln15;
        bfr[nt] = *(const s16x8*)&Ws[PERMC(row, ks * 4 + hf)];
      }
#pragma unroll
      for (int mt = 0; mt < 2; ++mt)
#pragma unroll
        for (int nt = 0; nt < 8; ++nt)
          acc[mt][nt] = MFMA16(af[mt], bfr[nt], acc[mt][nt]);
    }
  }
  float g8[8], be8[8], bf8[8];
#pragma unroll
  for (int nt = 0; nt < 8; ++nt) {
    int col = 128 * nh + 16 * nt + ln15;
    g8[nt] = gam[col]; be8[nt] = bet[col]; bf8[nt] = bfc[col];
  }
#pragma unroll
  for (int mt = 0; mt < 2; ++mt) {
    int mlb = 32 * mh + 16 * mt + 4 * quad;
    uint2 xv2[8];
#pragma unroll
    for (int nt = 0; nt < 8; ++nt) {            // xe skip: 4 consecutive t per lane
      int col = 128 * nh + 16 * nt + ln15;
      xv2[nt] = *(const uint2*)(xeT + (size_t)(b * CHN + col) * XROW + PREPAD + tin + mlb);
    }
#pragma unroll
    for (int r = 0; r < 4; ++r) {
      int ml = mlb + r;
      float s1 = 0.f, s2 = 0.f;
#pragma unroll
      for (int nt = 0; nt < 8; ++nt) {
        float t2 = acc[mt][nt][r] + bf8[nt];
        float xv = bf2f(((const unsigned short*)&xv2[nt])[r]);
        float y2 = geluf(t2) + xv;
        acc[mt][nt][r] = y2;
        s1 += y2; s2 += y2 * y2;
      }
      s1 += __shfl_xor(s1, 1); s2 += __shfl_xor(s2, 1);
      s1 += __shfl_xor(s1, 2); s2 += __shfl_xor(s2, 2);
      s1 += __shfl_xor(s1, 4); s2 += __shfl_xor(s2, 4);
      s1 += __shfl_xor(s1, 8); s2 += __shfl_xor(s2, 8);
      if (ln15 == 0) { pl[ml][nh][0] = s1; pl[ml][nh][1] = s2; }
    }
  }
  __syncthreads();
#pragma unroll
  for (int mt = 0; mt < 2; ++mt) {
#pragma unroll
    for (int r = 0; r < 4; ++r) {
      int ml = 32 * mh + 16 * mt + 4 * quad + r;
      float s1 = pl[ml][0][0] + pl[ml][1][0];
      float s2 = pl[ml][0][1] + pl[ml][1][1];
      float mu = s1 * (1.f / 256.f);
      float var = s2 * (1.f / 256.f) - mu * mu;
      float ri = rsqrtf(var + 1e-5f);
#pragma unroll
      for (int nt = 0; nt < 8; ++nt) {
        int col = 128 * nh + 16 * nt + ln15;
        float yn = (acc[mt][nt][r] - mu) * ri * g8[nt] + be8[nt];
        y2n[(M0 + ml) * CHN + col] = f2bf(yn);
      }
    }
  }
}

// ------------------- GEMM3: y = y2n W_dec^T + b_dec (fp32 out) + maxy atomics
__global__ __launch_bounds__(256) void k_gemm3(const unsigned short* y2n,
                                               const unsigned short* wb, const float* bd,
                                               float* yout, unsigned int* maxy) {
  __shared__ __align__(16) unsigned short Ws[256 * 64];
  __shared__ __align__(16) unsigned short Asb[64 * 64];
  int tid = threadIdx.x, lane = tid & 63, wv = tid >> 6;
  int ln15 = lane & 15, hf = lane >> 4, quad = hf;
  size_t M0 = (size_t)blockIdx.x * 64;           // grid 1024
  int b = (int)(M0 >> 13);
  int mh = wv & 1, nh = wv >> 1;
  f32x4 acc[2][8];
#pragma unroll
  for (int i = 0; i < 2; ++i)
#pragma unroll
    for (int j = 0; j < 8; ++j) { acc[i][j][0]=0.f; acc[i][j][1]=0.f; acc[i][j][2]=0.f; acc[i][j][3]=0.f; }

  for (int k0 = 0; k0 < CHN; k0 += 64) {
    __syncthreads();
#pragma unroll
    for (int i = 0; i < 8; ++i) {               // W: 2048 chunks
      int p = 512 * wv + 64 * i + lane;
      int row = p >> 3, h = (p & 7) ^ (row & 7);
      gll16(wb + (size_t)row * CHN + k0 + h * 8, &Ws[(512 * wv + 64 * i) * 8]);
    }
#pragma unroll
    for (int i = 0; i < 2; ++i) {               // A: 512 chunks
      int p = 128 * wv + 64 * i + lane;
      int row = p >> 3, h = (p & 7) ^ (row & 7);
      gll16(y2n + (M0 + row) * CHN + k0 + h * 8, &Asb[(128 * wv + 64 * i) * 8]);
    }
    __syncthreads();
#pragma unroll
    for (int ks = 0; ks < 2; ++ks) {
      s16x8 af[2], bfr[8];
#pragma unroll
      for (int mt = 0; mt < 2; ++mt) {
        int row = 32 * mh + 16 * mt + ln15;
        af[mt] = *(const s16x8*)&Asb[PERMC(row, ks * 4 + hf)];
      }
#pragma unroll
      for (int nt = 0; nt < 8; ++nt) {
        int row = 128 * nh + 16 * nt + ln15;
        bfr[nt] = *(const s16x8*)&Ws[PERMC(row, ks * 4 + hf)];
      }
#pragma unroll
      for (int mt = 0; mt < 2; ++mt)
#pragma unroll
        for (int nt = 0; nt < 8; ++nt)
          acc[mt][nt] = MFMA16(af[mt], bfr[nt], acc[mt][nt]);
    }
  }
  float bd8[8];
#pragma unroll
  for (int nt = 0; nt < 8; ++nt) bd8[nt] = bd[128 * nh + 16 * nt + ln15];
#pragma unroll
  for (int mt = 0; mt < 2; ++mt)
#pragma unroll
    for (int r = 0; r < 4; ++r) {
      int ml = 32 * mh + 16 * mt + 4 * quad + r;
#pragma unroll
      for (int nt = 0; nt < 8; ++nt) {
        int col = 128 * nh + 16 * nt + ln15;
        float v = acc[mt][nt][r] + bd8[nt];
        acc[mt][nt][r] = v;
        yout[(M0 + ml) * CHN + col] = v;
      }
    }
#pragma unroll
  for (int nt = 0; nt < 8; ++nt) {
    int col = 128 * nh + 16 * nt + ln15;
    float mv = 0.f;
#pragma unroll
    for (int mt = 0; mt < 2; ++mt)
#pragma unroll
      for (int r = 0; r < 4; ++r) mv = fmaxf(mv, fabsf(acc[mt][nt][r]));
    mv = fmaxf(mv, __shfl_xor(mv, 16));
    mv = fmaxf(mv, __shfl_xor(mv, 32));
    if (quad == 0) atomicMax(&maxy[b * CHN + col], __float_as_uint(mv));
  }
}

// ------------------------------------------------------------ h = my/(mx+eps)
__global__ __launch_bounds__(256) void k_hfin(const unsigned int* maxxe,
                                              const unsigned int* maxy, float* hout) {
  int i = blockIdx.x * 256 + threadIdx.x;        // grid 8
  if (i < BSZ * CHN) {
    float mx = __uint_as_float(maxxe[i]);
    float my = __uint_as_float(maxy[i]);
    hout[i] = my / (mx + 1e-6f);
  }
}

// ---------------------------------------------------------------------------
extern "C" void kernel_launch(void* const* d_in, const int* in_sizes, int n_in,
                              void* d_out, int out_size, void* d_ws, size_t ws_size,
                              hipStream_t stream) {
  const float* x   = (const float*)d_in[0];
  const float* A   = (const float*)d_in[1];
  const float* Bp  = (const float*)d_in[2];
  const float* h0  = (const float*)d_in[3];
  const float* We  = (const float*)d_in[4];
  const float* be  = (const float*)d_in[5];
  const float* Wf  = (const float*)d_in[6];
  const float* bfc = (const float*)d_in[7];
  const float* gam = (const float*)d_in[8];
  const float* bet = (const float*)d_in[9];
  const float* Wd  = (const float*)d_in[10];
  const float* bd  = (const float*)d_in[11];

  char* ws = (char*)d_ws;
  unsigned short* y1  = (unsigned short*)(ws + 0);          // 33554432 B
  unsigned short* afr = (unsigned short*)(ws + 33554432);   //  4456448 B
  unsigned short* web = (unsigned short*)(ws + 38010880);   //   131072 B
  unsigned short* wfb = (unsigned short*)(ws + 38141952);
  unsigned short* wdb = (unsigned short*)(ws + 38273024);
  unsigned int*  maxxe = (unsigned int*)(ws + 38404096);    //     8192 B
  unsigned int*  maxy  = (unsigned int*)(ws + 38412288);    //     8192 B

  unsigned short* xeT = (unsigned short*)d_out;             // scratch: 35.8 MB
  float* yout = (float*)d_out;
  float* hout = yout + YELEMS;

  k_prep<<<768, 256, 0, stream>>>(We, Wf, Wd, web, wfb, wdb);
  k_zero<<<548, 256, 0, stream>>>(xeT, (uint4*)maxxe);
  k_kgen<<<64, 256, 0, stream>>>(A, Bp, afr);
  k_gemm1<<<1024, 256, 0, stream>>>(x, web, be, xeT, maxxe);
  k_conv<<<2048, 256, 0, stream>>>(xeT, afr, y1, h0);
  k_gemm2<<<1024, 256, 0, stream>>>(y1, wfb, bfc, xeT, gam, bet, y1);
  k_gemm3<<<1024, 256, 0, stream>>>(y1, wdb, bd, yout, maxy);
  k_hfin<<<8, 256, 0, stream>>>(maxxe, maxy, hout);
}